// Round 6
// baseline (2040.499 us; speedup 1.0000x reference)
//
#include <hip/hip_runtime.h>
#include <hip/hip_fp16.h>

#define N_NODES 50000
#define N_EDGES 800000
#define N_GRAPHS 256
#define N_LAYERS 3
#define DIM 300
#define NFEAT 128
#define EFEAT 16
#define OUTD 128
#define BN_EPS 1e-5f
#define HSTRIDE 304   // fp16 node-row stride (300 + pad)

typedef __attribute__((ext_vector_type(8))) short bfrag8;   // 8 bf16 = 4 VGPR (MFMA A/B operand)
typedef __attribute__((ext_vector_type(4))) float facc4;    // MFMA C/D
typedef __attribute__((ext_vector_type(4))) unsigned short us4;
typedef __attribute__((ext_vector_type(8))) unsigned short us8;
typedef __attribute__((ext_vector_type(4))) unsigned int ui4;

// ---------------- bf16 helpers (RNE) + hi/lo split ----------------
__device__ __forceinline__ unsigned short f2bf(float f) {
    unsigned u = __float_as_uint(f);
    unsigned r = ((u >> 16) & 1u) + 0x7fffu;
    return (unsigned short)((u + r) >> 16);
}
__device__ __forceinline__ float bf2f(unsigned short h) {
    return __uint_as_float(((unsigned)h) << 16);
}
__device__ __forceinline__ void split2(float v, unsigned short& h, unsigned short& l) {
    h = f2bf(v);
    l = f2bf(v - bf2f(h));
}
// fp16 pack/unpack (single v_cvt each)
__device__ __forceinline__ unsigned short f2h(float f) {
    return __half_as_ushort(__float2half(f));
}
__device__ __forceinline__ float h2f(unsigned short u) {
    return __half2float(__ushort_as_half(u));
}

// v_dot2_f32_bf16: 2 bf16 MACs per instruction. Guarded: if the builtin is
// unavailable the gather falls back to the v7 FMA loop.
#if __has_builtin(__builtin_amdgcn_fdot2_f32_bf16)
#define GATHER_DOT2 1
typedef __attribute__((ext_vector_type(2))) __bf16 bf16x2_t;
__device__ __forceinline__ float dot2bf(unsigned a, unsigned b, float c) {
    return __builtin_amdgcn_fdot2_f32_bf16(
        __builtin_bit_cast(bf16x2_t, a), __builtin_bit_cast(bf16x2_t, b), c, false);
}
#else
#define GATHER_DOT2 0
#endif

// async global->LDS, 16B per lane. LDS dest = uniform base + lane*16 (HW rule).
__device__ __forceinline__ void load_lds16(const void* gsrc, void* ldsdst) {
    __builtin_amdgcn_global_load_lds(
        (const __attribute__((address_space(1))) unsigned int*)gsrc,
        (__attribute__((address_space(3))) unsigned int*)ldsdst,
        16, 0, 0);
}

#define MFMA16(a, b, c) __builtin_amdgcn_mfma_f32_16x16x32_bf16(a, b, c, 0, 0, 0)

// ---------------------------------------------------------------------------
// fp32 -> bf16 (hi only), vectorized
// ---------------------------------------------------------------------------
__global__ __launch_bounds__(256) void tobf4(
    const float* __restrict__ x, unsigned short* __restrict__ H, int n4)
{
    int i = blockIdx.x * 256 + threadIdx.x;
    if (i >= n4) return;
    float4 v = ((const float4*)x)[i];
    us4 h;
    h.x = f2bf(v.x); h.y = f2bf(v.y); h.z = f2bf(v.z); h.w = f2bf(v.w);
    ((us4*)H)[i] = h;
}

// ---------------------------------------------------------------------------
// hn fp32 [N][300] -> fp16 row table hnb [N][304] (run once after encoder)
// ---------------------------------------------------------------------------
__global__ __launch_bounds__(256) void toh_row(
    const float* __restrict__ hn, unsigned short* __restrict__ hnb)
{
    int i = blockIdx.x * 256 + threadIdx.x;
    if (i >= N_NODES * 76) return;
    int row = i / 76;
    int q = i - row * 76;
    us4 o;
    if (q < 75) {
        float4 v = *(const float4*)&hn[(size_t)row * DIM + 4 * q];
        o.x = f2h(v.x); o.y = f2h(v.y); o.z = f2h(v.z); o.w = f2h(v.w);
    } else {
        o.x = 0; o.y = 0; o.z = 0; o.w = 0;
    }
    *(us4*)&hnb[(size_t)row * HSTRIDE + 4 * q] = o;
}

// ---------------------------------------------------------------------------
// weight conversion: W fp32 [K][N] -> transposed padded hi/lo planes [Np][Kp]
// ---------------------------------------------------------------------------
__global__ __launch_bounds__(256) void conv_wt(
    const float* __restrict__ W, unsigned short* __restrict__ H,
    unsigned short* __restrict__ L, int K, int N, int Kp, int Np)
{
    int idx = blockIdx.x * 256 + threadIdx.x;
    if (idx >= Np * Kp) return;
    int n = idx / Kp;
    int k = idx - n * Kp;
    float v = (n < N && k < K) ? W[(size_t)k * N + n] : 0.f;
    unsigned short h, l;
    split2(v, h, l);
    H[idx] = h;
    L[idx] = l;
}

// ---------------------------------------------------------------------------
// bf16 MFMA GEMM: A plain bf16 [M][Kp]; B transposed hi/lo planes [Np][Kp].
// acc = Ah*Bh + Ah*Bl (2 MFMA/tile). Block 128x128, BK=32, 4 waves 2x2.
// GRID: blockIdx.x = N-block (fast-varying) so consecutive blocks share the
// same A row-tile -> A L2 reuse across column blocks. blockIdx.y = M-block.
// LDS 24KB: A | Bh | Bl. Optional column-stat epilogue (BN).
// ---------------------------------------------------------------------------
__global__ __launch_bounds__(256, 2) void gemm_pp(
    const unsigned short* __restrict__ Ah,
    const unsigned short* __restrict__ Bth, const unsigned short* __restrict__ Btl,
    const float* __restrict__ bias, float* __restrict__ C,
    int M, int N, int Kp, float* __restrict__ stats)
{
    __shared__ unsigned short lds[12288];   // 24 KB
    const int tid = threadIdx.x;
    const int lane = tid & 63;
    const int w = tid >> 6;
    const int m0 = blockIdx.y * 128;
    const int n0 = blockIdx.x * 128;
    const int wm = (w & 1) * 64;
    const int wn = (w >> 1) * 64;

    const int srow = lane >> 2;
    const int scol = (lane & 3) * 8;

    const unsigned short* gp[6];
    unsigned loff[6];
#pragma unroll
    for (int i = 0; i < 6; ++i) {
        int c = w * 6 + i;
        const unsigned short* pl = (c < 8) ? Ah : (c < 16) ? Bth : Btl;
        int rowg;
        if (c < 8) {
            rowg = m0 + (c & 7) * 16 + srow;
            rowg = min(rowg, M - 1);
        } else {
            rowg = n0 + (c & 7) * 16 + srow;
        }
        gp[i] = pl + (size_t)rowg * Kp + scol;
        loff[i] = c * 512;
    }

    facc4 acc[4][4];
    facc4 zero = {0.f, 0.f, 0.f, 0.f};
#pragma unroll
    for (int i = 0; i < 4; ++i)
#pragma unroll
        for (int j = 0; j < 4; ++j) acc[i][j] = zero;

    const int fr = lane & 15;
    const int fq = (lane >> 4) * 8;

    for (int k0 = 0; k0 < Kp; k0 += 32) {
#pragma unroll
        for (int i = 0; i < 6; ++i) {
            load_lds16(gp[i], &lds[loff[i]]);
            gp[i] += 32;
        }
        __syncthreads();

        bfrag8 ah[4], bh[4], bl[4];
#pragma unroll
        for (int t = 0; t < 4; ++t) {
            int ar = wm + t * 16 + fr;
            ah[t] = *(const bfrag8*)&lds[ar * 32 + fq];
            int br = wn + t * 16 + fr;
            bh[t] = *(const bfrag8*)&lds[4096 + br * 32 + fq];
            bl[t] = *(const bfrag8*)&lds[8192 + br * 32 + fq];
        }
#pragma unroll
        for (int i = 0; i < 4; ++i)
#pragma unroll
            for (int j = 0; j < 4; ++j) {
                acc[i][j] = MFMA16(ah[i], bh[j], acc[i][j]);
                acc[i][j] = MFMA16(ah[i], bl[j], acc[i][j]);
            }
        __syncthreads();
    }

    // epilogue: C/D layout col=lane&15, row=(lane>>4)*4+reg
#pragma unroll
    for (int i = 0; i < 4; ++i)
#pragma unroll
        for (int j = 0; j < 4; ++j) {
            int col = n0 + wn + j * 16 + (lane & 15);
            if (col >= N) continue;
            float bv = bias[col];
#pragma unroll
            for (int r = 0; r < 4; ++r) {
                int row = m0 + wm + i * 16 + (lane >> 4) * 4 + r;
                if (row < M)
                    C[(size_t)row * N + col] = acc[i][j][r] + bv;
            }
        }

    if (stats != nullptr) {
#pragma unroll
        for (int j = 0; j < 4; ++j) {
            int col = n0 + wn + j * 16 + (lane & 15);
            float cs = 0.f, cq = 0.f;
            if (col < N) {
                float bv = bias[col];
#pragma unroll
                for (int i = 0; i < 4; ++i)
#pragma unroll
                    for (int r = 0; r < 4; ++r) {
                        int row = m0 + wm + i * 16 + (lane >> 4) * 4 + r;
                        if (row < M) {
                            float y = acc[i][j][r] + bv;
                            cs += y;
                            cq = fmaf(y, y, cq);
                        }
                    }
            }
            cs += __shfl_xor(cs, 16, 64); cq += __shfl_xor(cq, 16, 64);
            cs += __shfl_xor(cs, 32, 64); cq += __shfl_xor(cq, 32, 64);
            if ((lane >> 4) == 0 && col < N) {
                atomicAdd(&stats[col], cs);
                atomicAdd(&stats[N + col], cq);
            }
        }
    }
}

// ---------------------------------------------------------------------------
// bf16 MFMA GEMM, A fp32 with fused BN-affine+ReLU applied during staging
// (abn = [a K | b K], y = relu(x*a+b)) -> bf16 hi only. Grid transposed as
// gemm_pp (x=N-block) for A L2 reuse. Column-stat epilogue for BN2.
// ---------------------------------------------------------------------------
__global__ __launch_bounds__(256, 2) void gemm_af(
    const float* __restrict__ A, const unsigned short* __restrict__ Bth,
    const unsigned short* __restrict__ Btl, const float* __restrict__ bias,
    float* __restrict__ C, int M, int N, int K, int Kp,
    const float* __restrict__ abn, float* __restrict__ stats)
{
    __shared__ unsigned short lds[12288];
    const int tid = threadIdx.x;
    const int lane = tid & 63;
    const int w = tid >> 6;
    const int m0 = blockIdx.y * 128;
    const int n0 = blockIdx.x * 128;
    const int wm = (w & 1) * 64;
    const int wn = (w >> 1) * 64;

    const int srow = lane >> 2;
    const int scol = (lane & 3) * 8;

    const unsigned short* gpb[4];
    unsigned loffb[4];
#pragma unroll
    for (int i = 0; i < 4; ++i) {
        int c = w * 4 + i;
        const unsigned short* pl = (c < 8) ? Bth : Btl;
        int rowg = n0 + (c & 7) * 16 + srow;
        gpb[i] = pl + (size_t)rowg * Kp + scol;
        loffb[i] = 4096 + c * 512;
    }

    facc4 acc[4][4];
    facc4 zero = {0.f, 0.f, 0.f, 0.f};
#pragma unroll
    for (int i = 0; i < 4; ++i)
#pragma unroll
        for (int j = 0; j < 4; ++j) acc[i][j] = zero;

    const int fr = lane & 15;
    const int fq = (lane >> 4) * 8;

    for (int k0 = 0; k0 < Kp; k0 += 32) {
#pragma unroll
        for (int i = 0; i < 4; ++i) {
            load_lds16(gpb[i], &lds[loffb[i]]);
            gpb[i] += 32;
        }
        // A fp32 -> BN affine + relu -> bf16 into LDS (128 rows x 32 k)
#pragma unroll
        for (int i = 0; i < 4; ++i) {
            int idx = tid + i * 256;
            int row = idx >> 3;
            int q4 = idx & 7;
            int rg = min(m0 + row, M - 1);
            int kk = k0 + q4 * 4;
            us4 h;
            if (kk < K) {
                float4 v = *(const float4*)&A[(size_t)rg * K + kk];
                float4 sa = *(const float4*)&abn[kk];
                float4 sb = *(const float4*)&abn[K + kk];
                h.x = f2bf(fmaxf(fmaf(v.x, sa.x, sb.x), 0.f));
                h.y = f2bf(fmaxf(fmaf(v.y, sa.y, sb.y), 0.f));
                h.z = f2bf(fmaxf(fmaf(v.z, sa.z, sb.z), 0.f));
                h.w = f2bf(fmaxf(fmaf(v.w, sa.w, sb.w), 0.f));
            } else {
                h.x = 0; h.y = 0; h.z = 0; h.w = 0;
            }
            *(us4*)&lds[row * 32 + q4 * 4] = h;
        }
        __syncthreads();

        bfrag8 ah[4], bh[4], bl[4];
#pragma unroll
        for (int t = 0; t < 4; ++t) {
            int ar = wm + t * 16 + fr;
            ah[t] = *(const bfrag8*)&lds[ar * 32 + fq];
            int br = wn + t * 16 + fr;
            bh[t] = *(const bfrag8*)&lds[4096 + br * 32 + fq];
            bl[t] = *(const bfrag8*)&lds[8192 + br * 32 + fq];
        }
#pragma unroll
        for (int i = 0; i < 4; ++i)
#pragma unroll
            for (int j = 0; j < 4; ++j) {
                acc[i][j] = MFMA16(ah[i], bh[j], acc[i][j]);
                acc[i][j] = MFMA16(ah[i], bl[j], acc[i][j]);
            }
        __syncthreads();
    }

#pragma unroll
    for (int i = 0; i < 4; ++i)
#pragma unroll
        for (int j = 0; j < 4; ++j) {
            int col = n0 + wn + j * 16 + (lane & 15);
            if (col >= N) continue;
            float bv = bias[col];
#pragma unroll
            for (int r = 0; r < 4; ++r) {
                int row = m0 + wm + i * 16 + (lane >> 4) * 4 + r;
                if (row < M)
                    C[(size_t)row * N + col] = acc[i][j][r] + bv;
            }
        }

    if (stats != nullptr) {
#pragma unroll
        for (int j = 0; j < 4; ++j) {
            int col = n0 + wn + j * 16 + (lane & 15);
            float cs = 0.f, cq = 0.f;
            if (col < N) {
                float bv = bias[col];
#pragma unroll
                for (int i = 0; i < 4; ++i)
#pragma unroll
                    for (int r = 0; r < 4; ++r) {
                        int row = m0 + wm + i * 16 + (lane >> 4) * 4 + r;
                        if (row < M) {
                            float y = acc[i][j][r] + bv;
                            cs += y;
                            cq = fmaf(y, y, cq);
                        }
                    }
            }
            cs += __shfl_xor(cs, 16, 64); cq += __shfl_xor(cq, 16, 64);
            cs += __shfl_xor(cs, 32, 64); cq += __shfl_xor(cq, 32, 64);
            if ((lane >> 4) == 0 && col < N) {
                atomicAdd(&stats[col], cs);
                atomicAdd(&stats[N + col], cq);
            }
        }
    }
}

// ---------------------------------------------------------------------------
// CSR build (dst-sorted). P[v] = end offset after fill.
// ---------------------------------------------------------------------------
__global__ __launch_bounds__(256) void csr_count(const int* __restrict__ dst, int* __restrict__ P)
{
    int e = blockIdx.x * 256 + threadIdx.x;
    if (e < N_EDGES) atomicAdd(&P[dst[e] + 1], 1);
}

__global__ __launch_bounds__(1024) void csr_scan(int* __restrict__ P)
{
    __shared__ int part[1024];
    const int t = threadIdx.x;
    const int CH = 49;
    int i0 = t * CH;
    int s = 0;
    for (int i = i0; i < i0 + CH; ++i) {
        if (i <= N_NODES) { s += P[i]; P[i] = s; }
    }
    part[t] = s;
    __syncthreads();
    if (t == 0) {
        int run = 0;
        for (int k = 0; k < 1024; ++k) { int tmp = part[k]; part[k] = run; run += tmp; }
    }
    __syncthreads();
    int off = part[t];
    for (int i = i0; i < i0 + CH; ++i) {
        if (i <= N_NODES) P[i] += off;
    }
}

__global__ __launch_bounds__(256) void csr_fill(
    const int* __restrict__ dst, int* __restrict__ P, int* __restrict__ eids)
{
    int e = blockIdx.x * 256 + threadIdx.x;
    if (e < N_EDGES) {
        int pos = atomicAdd(&P[dst[e]], 1);
        eids[pos] = e;
    }
}

// ---------------------------------------------------------------------------
// Re-sort src + edge_feat(->bf16) into CSR edge order. Runs once.
// ---------------------------------------------------------------------------
__global__ __launch_bounds__(256) void edge_pack_bf(
    const int* __restrict__ src, const int* __restrict__ eids,
    const float* __restrict__ edge_feat, int* __restrict__ es,
    unsigned short* __restrict__ efsb)
{
    int j = blockIdx.x * 256 + threadIdx.x;
    if (j >= N_EDGES) return;
    int e = eids[j];
    es[j] = src[e];
    const float* sp = edge_feat + (size_t)e * EFEAT;
    us8 o0, o1;
#pragma unroll
    for (int k = 0; k < 8; ++k) {
        o0[k] = f2bf(sp[k]);
        o1[k] = f2bf(sp[8 + k]);
    }
    *(us8*)&efsb[(size_t)j * EFEAT] = o0;
    *(us8*)&efsb[(size_t)j * EFEAT + 8] = o1;
}

// ---------------------------------------------------------------------------
// Gather aggregation v12: v11 structure (wave/node, x4 edge unroll, dot2
// ef@eW) with node rows read from the fp16 table hnb [N][304] instead of
// fp32 hn. Halves the dominant gathered-row traffic (960->480 MB logical;
// 30.4MB table ~fits aggregate L2). fp16 keeps 10 mantissa bits (rel err
// 2^-11) so accuracy is essentially unchanged vs fp32 rows. Residual also
// from hnb. v11 counters: VALU 55%, HBM 2.6TB/s, FETCH 522MB -> memory-bound.
// ---------------------------------------------------------------------------
__global__ __launch_bounds__(256) void gather_agg7(
    const unsigned short* __restrict__ hnb, const unsigned short* __restrict__ efsb,
    const int* __restrict__ es, const int* __restrict__ P,
    const float* __restrict__ eW, const float* __restrict__ eb,
    unsigned short* __restrict__ aggH)
{
    const int v = blockIdx.x * 4 + (threadIdx.x >> 6);
    if (v >= N_NODES) return;
    const int lane = threadIdx.x & 63;

    float acc[5];
    float ebv[5];
#if GATHER_DOT2
    unsigned wpk[8][5];   // feature-pair p=(2p,2p+1), dim chunk c: packed bf16
#pragma unroll
    for (int c = 0; c < 5; ++c) {
        int d = lane + 64 * c;
        bool dv = d < DIM;
        acc[c] = dv ? h2f(hnb[(size_t)v * HSTRIDE + d]) : 0.f;
        ebv[c] = dv ? eb[d] : 0.f;
#pragma unroll
        for (int p = 0; p < 8; ++p) {
            unsigned short h0 = dv ? f2bf(eW[(2 * p) * DIM + d]) : (unsigned short)0;
            unsigned short h1 = dv ? f2bf(eW[(2 * p + 1) * DIM + d]) : (unsigned short)0;
            wpk[p][c] = (unsigned)h0 | ((unsigned)h1 << 16);
        }
    }
#else
    float wr[EFEAT][5];
#pragma unroll
    for (int c = 0; c < 5; ++c) {
        int d = lane + 64 * c;
        bool dv = d < DIM;
        acc[c] = dv ? h2f(hnb[(size_t)v * HSTRIDE + d]) : 0.f;
        ebv[c] = dv ? eb[d] : 0.f;
#pragma unroll
        for (int k = 0; k < EFEAT; ++k)
            wr[k][c] = dv ? eW[k * DIM + d] : 0.f;
    }
#endif

    const int j0 = (v == 0) ? 0 : P[v - 1];
    const int j1 = P[v];

    int j = j0;
    for (; j + 4 <= j1; j += 4) {
        int s0 = __builtin_amdgcn_readfirstlane(es[j]);
        int s1 = __builtin_amdgcn_readfirstlane(es[j + 1]);
        int s2 = __builtin_amdgcn_readfirstlane(es[j + 2]);
        int s3 = __builtin_amdgcn_readfirstlane(es[j + 3]);
        const unsigned short* __restrict__ h0 = hnb + (size_t)s0 * HSTRIDE;
        const unsigned short* __restrict__ h1 = hnb + (size_t)s1 * HSTRIDE;
        const unsigned short* __restrict__ h2p = hnb + (size_t)s2 * HSTRIDE;
        const unsigned short* __restrict__ h3 = hnb + (size_t)s3 * HSTRIDE;
        float hv[4][5];
#pragma unroll
        for (int c = 0; c < 5; ++c) {
            int d = lane + 64 * c;
            bool dv = d < DIM;
            hv[0][c] = dv ? h2f(h0[d]) : 0.f;
            hv[1][c] = dv ? h2f(h1[d]) : 0.f;
            hv[2][c] = dv ? h2f(h2p[d]) : 0.f;
            hv[3][c] = dv ? h2f(h3[d]) : 0.f;
        }
#if GATHER_DOT2
        ui4 pa[4][2];
#pragma unroll
        for (int u = 0; u < 4; ++u) {
            pa[u][0] = *(const ui4*)&efsb[(size_t)(j + u) * EFEAT];
            pa[u][1] = *(const ui4*)&efsb[(size_t)(j + u) * EFEAT + 8];
        }
#pragma unroll
        for (int u = 0; u < 4; ++u) {
#pragma unroll
            for (int c = 0; c < 5; ++c) {
                float he = ebv[c];
                he = dot2bf(pa[u][0][0], wpk[0][c], he);
                he = dot2bf(pa[u][0][1], wpk[1][c], he);
                he = dot2bf(pa[u][0][2], wpk[2][c], he);
                he = dot2bf(pa[u][0][3], wpk[3][c], he);
                he = dot2bf(pa[u][1][0], wpk[4][c], he);
                he = dot2bf(pa[u][1][1], wpk[5][c], he);
                he = dot2bf(pa[u][1][2], wpk[6][c], he);
                he = dot2bf(pa[u][1][3], wpk[7][c], he);
                acc[c] += fmaxf(hv[u][c] + he, 0.f);
            }
        }
#else
        us8 pk[4][2];
#pragma unroll
        for (int u = 0; u < 4; ++u) {
            pk[u][0] = *(const us8*)&efsb[(size_t)(j + u) * EFEAT];
            pk[u][1] = *(const us8*)&efsb[(size_t)(j + u) * EFEAT + 8];
        }
#pragma unroll
        for (int u = 0; u < 4; ++u) {
            float ef[EFEAT];
#pragma unroll
            for (int k = 0; k < 8; ++k) {
                ef[k] = bf2f(pk[u][0][k]);
                ef[8 + k] = bf2f(pk[u][1][k]);
            }
#pragma unroll
            for (int c = 0; c < 5; ++c) {
                float he = ebv[c];
#pragma unroll
                for (int k = 0; k < EFEAT; ++k) he = fmaf(ef[k], wr[k][c], he);
                acc[c] += fmaxf(hv[u][c] + he, 0.f);
            }
        }
#endif
    }
    for (; j < j1; ++j) {
        int s = __builtin_amdgcn_readfirstlane(es[j]);
        const unsigned short* __restrict__ hp = hnb + (size_t)s * HSTRIDE;
        float hv[5];
#pragma unroll
        for (int c = 0; c < 5; ++c) {
            int d = lane + 64 * c;
            hv[c] = (d < DIM) ? h2f(hp[d]) : 0.f;
        }
#if GATHER_DOT2
        ui4 p0 = *(const ui4*)&efsb[(size_t)j * EFEAT];
        ui4 p1 = *(const ui4*)&efsb[(size_t)j * EFEAT + 8];
#pragma unroll
        for (int c = 0; c < 5; ++c) {
            float he = ebv[c];
            he = dot2bf(p0[0], wpk[0][c], he);
            he = dot2bf(p0[1], wpk[1][c], he);
            he = dot2bf(p0[2], wpk[2][c], he);
            he = dot2bf(p0[3], wpk[3][c], he);
            he = dot2bf(p1[0], wpk[4][c], he);
            he = dot2bf(p1[1], wpk[5][c], he);
            he = dot2bf(p1[2], wpk[6][c], he);
            he = dot2bf(p1[3], wpk[7][c], he);
            acc[c] += fmaxf(hv[c] + he, 0.f);
        }
#else
        us8 p0 = *(const us8*)&efsb[(size_t)j * EFEAT];
        us8 p1 = *(const us8*)&efsb[(size_t)j * EFEAT + 8];
        float ef[EFEAT];
#pragma unroll
        for (int k = 0; k < 8; ++k) {
            ef[k] = bf2f(p0[k]);
            ef[8 + k] = bf2f(p1[k]);
        }
#pragma unroll
        for (int c = 0; c < 5; ++c) {
            float he = ebv[c];
#pragma unroll
            for (int k = 0; k < EFEAT; ++k) he = fmaf(ef[k], wr[k][c], he);
            acc[c] += fmaxf(hv[c] + he, 0.f);
        }
#endif
    }

#pragma unroll
    for (int c = 0; c < 5; ++c)
        aggH[(size_t)v * 320 + lane + 64 * c] = f2bf(acc[c]);
}

// ---------------------------------------------------------------------------
// BN finalize + apply (apply writes the fp16 node table for the next gather)
// ---------------------------------------------------------------------------
__global__ __launch_bounds__(256) void bn_finalize(
    const float* __restrict__ stats, const float* __restrict__ g,
    const float* __restrict__ beta, float* __restrict__ ab, int C)
{
    int c = blockIdx.x * 256 + threadIdx.x;
    if (c >= C) return;
    const float invN = 1.f / (float)N_NODES;
    float m = stats[c] * invN;
    float v = stats[C + c] * invN - m * m;
    float a = g[c] * rsqrtf(v + BN_EPS);
    ab[c] = a;
    ab[C + c] = beta[c] - m * a;
}

// y = relu(x*a+b) -> fp16 rows [N][HSTRIDE]  (x = h2 fp32 [N][300])
__global__ __launch_bounds__(256) void bn_apply_h(
    const float* __restrict__ x, const float* __restrict__ ab,
    unsigned short* __restrict__ hnb)
{
    int i = blockIdx.x * 256 + threadIdx.x;
    if (i >= N_NODES * 75) return;
    int row = i / 75;
    int q = i - row * 75;
    int c = 4 * q;
    float4 v = ((const float4*)x)[i];
    const float* a = ab + c;
    const float* bb = ab + DIM + c;
    us4 o;
    o.x = f2h(fmaxf(fmaf(v.x, a[0], bb[0]), 0.f));
    o.y = f2h(fmaxf(fmaf(v.y, a[1], bb[1]), 0.f));
    o.z = f2h(fmaxf(fmaf(v.z, a[2], bb[2]), 0.f));
    o.w = f2h(fmaxf(fmaf(v.w, a[3], bb[3]), 0.f));
    *(us4*)&hnb[(size_t)row * HSTRIDE + c] = o;
}

// ---------------------------------------------------------------------------
// Mean pooling fused with last BN affine: hg = a*mean(h2)+b.
// ---------------------------------------------------------------------------
__global__ __launch_bounds__(256) void pool_seg_bn(
    const float* __restrict__ h2, const int* __restrict__ gid,
    const float* __restrict__ ab, float* __restrict__ hg)
{
    const int g = blockIdx.x;
    int lo = 0, hi = N_NODES;
    while (lo < hi) { int mid = (lo + hi) >> 1; if (gid[mid] < g) lo = mid + 1; else hi = mid; }
    int lo2 = lo, hi2 = N_NODES;
    while (lo2 < hi2) { int mid = (lo2 + hi2) >> 1; if (gid[mid] < g + 1) lo2 = mid + 1; else hi2 = mid; }
    const float inv = 1.f / fmaxf((float)(lo2 - lo), 1.f);
    for (int d = threadIdx.x; d < DIM; d += 256) {
        float s = 0.f;
        for (int r = lo; r < lo2; ++r) s += h2[(size_t)r * DIM + d];
        hg[(size_t)g * DIM + d] = fmaf(s * inv, ab[d], ab[DIM + d]);
    }
}

// fp32 tiled sgemm for the tiny prediction head
#define TS 64
#define BK 16
#define ASP 68

__global__ __launch_bounds__(256) void sgemm_bias(
    const float* __restrict__ A, const float* __restrict__ B,
    const float* __restrict__ bias, float* __restrict__ C,
    int M, int Ncol, int K)
{
    __shared__ float As[BK][ASP];
    __shared__ float Bs[BK][TS];
    const int tid = threadIdx.x;
    const int bm = blockIdx.x * TS;
    const int bn = blockIdx.y * TS;
    const int tm = (tid >> 4) * 4;
    const int tn = (tid & 15) * 4;
    float acc[4][4] = {};

    for (int k0 = 0; k0 < K; k0 += BK) {
#pragma unroll
        for (int i = 0; i < 4; ++i) {
            int idx = tid + i * 256;
            int m = idx >> 4;
            int k = idx & 15;
            int row = bm + m, kk = k0 + k;
            float v = 0.f;
            if (row < M && kk < K) v = A[(size_t)row * K + kk];
            As[k][m] = v;
        }
#pragma unroll
        for (int i = 0; i < 4; ++i) {
            int idx = tid + i * 256;
            int k = idx >> 6;
            int n = idx & 63;
            int col = bn + n, kk = k0 + k;
            float v = 0.f;
            if (col < Ncol && kk < K) v = B[(size_t)kk * Ncol + col];
            Bs[k][n] = v;
        }
        __syncthreads();
#pragma unroll
        for (int k = 0; k < BK; ++k) {
            float4 av = *(const float4*)&As[k][tm];
            float4 bv = *(const float4*)&Bs[k][tn];
            float a4[4] = {av.x, av.y, av.z, av.w};
            float b4[4] = {bv.x, bv.y, bv.z, bv.w};
#pragma unroll
            for (int i = 0; i < 4; ++i)
#pragma unroll
                for (int j = 0; j < 4; ++j)
                    acc[i][j] = fmaf(a4[i], b4[j], acc[i][j]);
        }
        __syncthreads();
    }

#pragma unroll
    for (int i = 0; i < 4; ++i) {
        int row = bm + tm + i;
        if (row >= M) continue;
#pragma unroll
        for (int j = 0; j < 4; ++j) {
            int col = bn + tn + j;
            if (col < Ncol)
                C[(size_t)row * Ncol + col] = acc[i][j] + bias[col];
        }
    }
}

// ---------------------------------------------------------------------------
extern "C" void kernel_launch(void* const* d_in, const int* in_sizes, int n_in,
                              void* d_out, int out_size, void* d_ws, size_t ws_size,
                              hipStream_t stream)
{
    const float* node_feat = (const float*)d_in[0];
    const float* edge_feat = (const float*)d_in[1];
    const int*   src       = (const int*)d_in[2];
    const int*   dst       = (const int*)d_in[3];
    const int*   gid       = (const int*)d_in[4];
    const float* node_W = (const float*)d_in[6];
    const float* node_b = (const float*)d_in[7];
    const float* edge_W = (const float*)d_in[8];
    const float* edge_b = (const float*)d_in[9];
    const float* W1  = (const float*)d_in[10];
    const float* b1  = (const float*)d_in[11];
    const float* g1  = (const float*)d_in[12];
    const float* be1 = (const float*)d_in[13];
    const float* W2  = (const float*)d_in[14];
    const float* b2  = (const float*)d_in[15];
    const float* g2  = (const float*)d_in[16];
    const float* be2 = (const float*)d_in[17];
    const float* pred_W = (const float*)d_in[18];
    const float* pred_b = (const float*)d_in[19];
    float* out = (float*)d_out;

    // ---- workspace layout (bytes), total < 248.73 MB (r9-proven) ----
    // hnb (fp16 node table, 30.4MB) aliases the head of x1: lifetime is
    // bn_apply_h(l) [or toh_row] -> gather(l+1); x1 is dead in that window
    // and gemm_pp(l+1) overwrites it only after gather(l+1) completes.
    char* base = (char*)d_ws;
    float* hn            = (float*)(base + 0);                 // 60,000,000
    float* h2            = hn;                                 // in-place
    float* x1            = (float*)(base + 60000000);          // 120,000,000
    unsigned short* nfH  = (unsigned short*)x1;                // alias (encoder only)
    unsigned short* hnb  = (unsigned short*)x1;                // alias (gather rows)
    unsigned short* aggH = (unsigned short*)(base + 180000000);// 32,000,000
    int*   es            = (int*)(base + 212000000);           // 3,200,000
    unsigned short* efsb = (unsigned short*)(base + 215200000);// 25,600,000
    unsigned short* wtH  = (unsigned short*)(base + 244000000);
    unsigned short* wtL  = (unsigned short*)(base + 244500000);
    int*   eids          = (int*)(base + 245000000);           // 3,200,000
    int*   P             = (int*)(base + 248200000);           // 200,004
    float* stats         = (float*)(base + 248400016);
    float* ab            = (float*)(base + 248407216);
    float* hg            = (float*)(base + 248414416);         // 307,200
    float* stats2        = stats + 1200;
    float* ab2           = ab + 1200;

    dim3 blk(256);

    // ---- node encoder: hn = node_feat @ node_W + node_b ----
    tobf4<<<dim3((N_NODES * NFEAT / 4 + 255) / 256), blk, 0, stream>>>(
        node_feat, nfH, N_NODES * NFEAT / 4);
    conv_wt<<<dim3((384 * 128 + 255) / 256), blk, 0, stream>>>(
        node_W, wtH, wtL, NFEAT, DIM, 128, 384);
    gemm_pp<<<dim3(3, 391), blk, 0, stream>>>(
        nfH, wtH, wtL, node_b, hn, N_NODES, DIM, 128, nullptr);
    // fp16 row table for the gather (overwrites nfH — dead after gemm)
    toh_row<<<dim3((N_NODES * 76 + 255) / 256), blk, 0, stream>>>(hn, hnb);

    // ---- CSR by dst + packed edge streams (layer-invariant, run once) ----
    hipMemsetAsync(P, 0, (N_NODES + 1) * sizeof(int), stream);
    csr_count<<<dim3((N_EDGES + 255) / 256), blk, 0, stream>>>(dst, P);
    csr_scan<<<dim3(1), dim3(1024), 0, stream>>>(P);
    csr_fill<<<dim3((N_EDGES + 255) / 256), blk, 0, stream>>>(dst, P, eids);
    edge_pack_bf<<<dim3((N_EDGES + 255) / 256), blk, 0, stream>>>(
        src, eids, edge_feat, es, efsb);

    for (int l = 0; l < N_LAYERS; ++l) {
        // aggH = bf16(hnb + sum relu(hnb[src] + he))  [N][320]
        gather_agg7<<<dim3((N_NODES + 3) / 4), blk, 0, stream>>>(
            hnb, efsb, es, P,
            edge_W + (size_t)l * EFEAT * DIM, edge_b + (size_t)l * DIM, aggH);

        hipMemsetAsync(stats, 0, 1800 * sizeof(float), stream);

        // x1 = agg @ W1 + b1   [N, 600]  (+ BN1 stats in epilogue)
        conv_wt<<<dim3((640 * 320 + 255) / 256), blk, 0, stream>>>(
            W1 + (size_t)l * DIM * 2 * DIM, wtH, wtL, DIM, 2 * DIM, 320, 640);
        gemm_pp<<<dim3(5, 391), blk, 0, stream>>>(
            aggH, wtH, wtL, b1 + (size_t)l * 2 * DIM, x1,
            N_NODES, 2 * DIM, 320, stats);
        bn_finalize<<<dim3(3), blk, 0, stream>>>(
            stats, g1 + (size_t)l * 2 * DIM, be1 + (size_t)l * 2 * DIM, ab, 2 * DIM);

        // h2(=hn) = relu(bn1(x1)) @ W2 + b2  (BN1 fused in staging; BN2 stats)
        conv_wt<<<dim3((384 * 608 + 255) / 256), blk, 0, stream>>>(
            W2 + (size_t)l * 2 * DIM * DIM, wtH, wtL, 2 * DIM, DIM, 608, 384);
        gemm_af<<<dim3(3, 391), blk, 0, stream>>>(
            x1, wtH, wtL, b2 + (size_t)l * DIM, h2, N_NODES, DIM, 2 * DIM, 608,
            ab, stats2);
        bn_finalize<<<dim3(2), blk, 0, stream>>>(
            stats2, g2 + (size_t)l * DIM, be2 + (size_t)l * DIM, ab2, DIM);

        // next-layer node table: hnb = fp16(relu(bn2(h2))) — last layer pools
        if (l < N_LAYERS - 1)
            bn_apply_h<<<dim3((N_NODES * 75 + 255) / 256), blk, 0, stream>>>(
                h2, ab2, hnb);
    }

    // ---- mean pool with fused last-BN affine + head ----
    pool_seg_bn<<<dim3(N_GRAPHS), blk, 0, stream>>>(h2, gid, ab2, hg);
    sgemm_bias<<<dim3((N_GRAPHS + 63) / 64, (OUTD + 63) / 64), blk, 0, stream>>>(
        hg, pred_W, pred_b, out, N_GRAPHS, OUTD, DIM);
}

// Round 7
// 1917.014 us; speedup vs baseline: 1.0644x; 1.0644x over previous
//
#include <hip/hip_runtime.h>
#include <hip/hip_fp16.h>

#define N_NODES 50000
#define N_EDGES 800000
#define N_GRAPHS 256
#define N_LAYERS 3
#define DIM 300
#define NFEAT 128
#define EFEAT 16
#define OUTD 128
#define BN_EPS 1e-5f
#define HSTRIDE 320   // fp16 node-row stride (300 + zero pad to 320)

typedef __attribute__((ext_vector_type(8))) short bfrag8;   // 8 bf16 = 4 VGPR (MFMA A/B operand)
typedef __attribute__((ext_vector_type(4))) float facc4;    // MFMA C/D
typedef __attribute__((ext_vector_type(4))) unsigned short us4;
typedef __attribute__((ext_vector_type(8))) unsigned short us8;
typedef __attribute__((ext_vector_type(4))) unsigned int ui4;

// ---------------- bf16 helpers (RNE) + hi/lo split ----------------
__device__ __forceinline__ unsigned short f2bf(float f) {
    unsigned u = __float_as_uint(f);
    unsigned r = ((u >> 16) & 1u) + 0x7fffu;
    return (unsigned short)((u + r) >> 16);
}
__device__ __forceinline__ float bf2f(unsigned short h) {
    return __uint_as_float(((unsigned)h) << 16);
}
__device__ __forceinline__ void split2(float v, unsigned short& h, unsigned short& l) {
    h = f2bf(v);
    l = f2bf(v - bf2f(h));
}
// fp16 pack/unpack (single v_cvt each)
__device__ __forceinline__ unsigned short f2h(float f) {
    return __half_as_ushort(__float2half(f));
}
__device__ __forceinline__ float h2f(unsigned short u) {
    return __half2float(__ushort_as_half(u));
}

// v_dot2_f32_bf16: 2 bf16 MACs per instruction. Guarded: if the builtin is
// unavailable the gather falls back to the FMA loop.
#if __has_builtin(__builtin_amdgcn_fdot2_f32_bf16)
#define GATHER_DOT2 1
typedef __attribute__((ext_vector_type(2))) __bf16 bf16x2_t;
__device__ __forceinline__ float dot2bf(unsigned a, unsigned b, float c) {
    return __builtin_amdgcn_fdot2_f32_bf16(
        __builtin_bit_cast(bf16x2_t, a), __builtin_bit_cast(bf16x2_t, b), c, false);
}
#else
#define GATHER_DOT2 0
#endif

// async global->LDS, 16B per lane. LDS dest = uniform base + lane*16 (HW rule).
__device__ __forceinline__ void load_lds16(const void* gsrc, void* ldsdst) {
    __builtin_amdgcn_global_load_lds(
        (const __attribute__((address_space(1))) unsigned int*)gsrc,
        (__attribute__((address_space(3))) unsigned int*)ldsdst,
        16, 0, 0);
}

#define MFMA16(a, b, c) __builtin_amdgcn_mfma_f32_16x16x32_bf16(a, b, c, 0, 0, 0)

// ---------------------------------------------------------------------------
// fp32 -> bf16 (hi only), vectorized
// ---------------------------------------------------------------------------
__global__ __launch_bounds__(256) void tobf4(
    const float* __restrict__ x, unsigned short* __restrict__ H, int n4)
{
    int i = blockIdx.x * 256 + threadIdx.x;
    if (i >= n4) return;
    float4 v = ((const float4*)x)[i];
    us4 h;
    h.x = f2bf(v.x); h.y = f2bf(v.y); h.z = f2bf(v.z); h.w = f2bf(v.w);
    ((us4*)H)[i] = h;
}

// ---------------------------------------------------------------------------
// hn fp32 [N][300] -> fp16 row table hnb [N][320] (zero pad 300..319)
// ---------------------------------------------------------------------------
__global__ __launch_bounds__(256) void toh_row(
    const float* __restrict__ hn, unsigned short* __restrict__ hnb)
{
    int i = blockIdx.x * 256 + threadIdx.x;
    if (i >= N_NODES * 80) return;
    int row = i / 80;
    int q = i - row * 80;
    us4 o;
    if (q < 75) {
        float4 v = *(const float4*)&hn[(size_t)row * DIM + 4 * q];
        o.x = f2h(v.x); o.y = f2h(v.y); o.z = f2h(v.z); o.w = f2h(v.w);
    } else {
        o.x = 0; o.y = 0; o.z = 0; o.w = 0;
    }
    *(us4*)&hnb[(size_t)row * HSTRIDE + 4 * q] = o;
}

// ---------------------------------------------------------------------------
// weight conversion: W fp32 [K][N] -> transposed padded hi/lo planes [Np][Kp]
// ---------------------------------------------------------------------------
__global__ __launch_bounds__(256) void conv_wt(
    const float* __restrict__ W, unsigned short* __restrict__ H,
    unsigned short* __restrict__ L, int K, int N, int Kp, int Np)
{
    int idx = blockIdx.x * 256 + threadIdx.x;
    if (idx >= Np * Kp) return;
    int n = idx / Kp;
    int k = idx - n * Kp;
    float v = (n < N && k < K) ? W[(size_t)k * N + n] : 0.f;
    unsigned short h, l;
    split2(v, h, l);
    H[idx] = h;
    L[idx] = l;
}

// ---------------------------------------------------------------------------
// bf16 MFMA GEMM: A plain bf16 [M][Kp]; B transposed hi/lo planes [Np][Kp].
// acc = Ah*Bh + Ah*Bl (2 MFMA/tile). Block 128x128, BK=32, 4 waves 2x2.
// GRID: blockIdx.x = N-block (fast-varying) so consecutive blocks share the
// same A row-tile -> A L2 reuse across column blocks. blockIdx.y = M-block.
// LDS 24KB: A | Bh | Bl. Optional column-stat epilogue (BN).
// ---------------------------------------------------------------------------
__global__ __launch_bounds__(256, 2) void gemm_pp(
    const unsigned short* __restrict__ Ah,
    const unsigned short* __restrict__ Bth, const unsigned short* __restrict__ Btl,
    const float* __restrict__ bias, float* __restrict__ C,
    int M, int N, int Kp, float* __restrict__ stats)
{
    __shared__ unsigned short lds[12288];   // 24 KB
    const int tid = threadIdx.x;
    const int lane = tid & 63;
    const int w = tid >> 6;
    const int m0 = blockIdx.y * 128;
    const int n0 = blockIdx.x * 128;
    const int wm = (w & 1) * 64;
    const int wn = (w >> 1) * 64;

    const int srow = lane >> 2;
    const int scol = (lane & 3) * 8;

    const unsigned short* gp[6];
    unsigned loff[6];
#pragma unroll
    for (int i = 0; i < 6; ++i) {
        int c = w * 6 + i;
        const unsigned short* pl = (c < 8) ? Ah : (c < 16) ? Bth : Btl;
        int rowg;
        if (c < 8) {
            rowg = m0 + (c & 7) * 16 + srow;
            rowg = min(rowg, M - 1);
        } else {
            rowg = n0 + (c & 7) * 16 + srow;
        }
        gp[i] = pl + (size_t)rowg * Kp + scol;
        loff[i] = c * 512;
    }

    facc4 acc[4][4];
    facc4 zero = {0.f, 0.f, 0.f, 0.f};
#pragma unroll
    for (int i = 0; i < 4; ++i)
#pragma unroll
        for (int j = 0; j < 4; ++j) acc[i][j] = zero;

    const int fr = lane & 15;
    const int fq = (lane >> 4) * 8;

    for (int k0 = 0; k0 < Kp; k0 += 32) {
#pragma unroll
        for (int i = 0; i < 6; ++i) {
            load_lds16(gp[i], &lds[loff[i]]);
            gp[i] += 32;
        }
        __syncthreads();

        bfrag8 ah[4], bh[4], bl[4];
#pragma unroll
        for (int t = 0; t < 4; ++t) {
            int ar = wm + t * 16 + fr;
            ah[t] = *(const bfrag8*)&lds[ar * 32 + fq];
            int br = wn + t * 16 + fr;
            bh[t] = *(const bfrag8*)&lds[4096 + br * 32 + fq];
            bl[t] = *(const bfrag8*)&lds[8192 + br * 32 + fq];
        }
#pragma unroll
        for (int i = 0; i < 4; ++i)
#pragma unroll
            for (int j = 0; j < 4; ++j) {
                acc[i][j] = MFMA16(ah[i], bh[j], acc[i][j]);
                acc[i][j] = MFMA16(ah[i], bl[j], acc[i][j]);
            }
        __syncthreads();
    }

    // epilogue: C/D layout col=lane&15, row=(lane>>4)*4+reg
#pragma unroll
    for (int i = 0; i < 4; ++i)
#pragma unroll
        for (int j = 0; j < 4; ++j) {
            int col = n0 + wn + j * 16 + (lane & 15);
            if (col >= N) continue;
            float bv = bias[col];
#pragma unroll
            for (int r = 0; r < 4; ++r) {
                int row = m0 + wm + i * 16 + (lane >> 4) * 4 + r;
                if (row < M)
                    C[(size_t)row * N + col] = acc[i][j][r] + bv;
            }
        }

    if (stats != nullptr) {
#pragma unroll
        for (int j = 0; j < 4; ++j) {
            int col = n0 + wn + j * 16 + (lane & 15);
            float cs = 0.f, cq = 0.f;
            if (col < N) {
                float bv = bias[col];
#pragma unroll
                for (int i = 0; i < 4; ++i)
#pragma unroll
                    for (int r = 0; r < 4; ++r) {
                        int row = m0 + wm + i * 16 + (lane >> 4) * 4 + r;
                        if (row < M) {
                            float y = acc[i][j][r] + bv;
                            cs += y;
                            cq = fmaf(y, y, cq);
                        }
                    }
            }
            cs += __shfl_xor(cs, 16, 64); cq += __shfl_xor(cq, 16, 64);
            cs += __shfl_xor(cs, 32, 64); cq += __shfl_xor(cq, 32, 64);
            if ((lane >> 4) == 0 && col < N) {
                atomicAdd(&stats[col], cs);
                atomicAdd(&stats[N + col], cq);
            }
        }
    }
}

// ---------------------------------------------------------------------------
// bf16 MFMA GEMM, A fp32 with fused BN-affine+ReLU applied during staging
// (abn = [a K | b K], y = relu(x*a+b)) -> bf16 hi only. Grid transposed as
// gemm_pp (x=N-block) for A L2 reuse. Column-stat epilogue for BN2.
// ---------------------------------------------------------------------------
__global__ __launch_bounds__(256, 2) void gemm_af(
    const float* __restrict__ A, const unsigned short* __restrict__ Bth,
    const unsigned short* __restrict__ Btl, const float* __restrict__ bias,
    float* __restrict__ C, int M, int N, int K, int Kp,
    const float* __restrict__ abn, float* __restrict__ stats)
{
    __shared__ unsigned short lds[12288];
    const int tid = threadIdx.x;
    const int lane = tid & 63;
    const int w = tid >> 6;
    const int m0 = blockIdx.y * 128;
    const int n0 = blockIdx.x * 128;
    const int wm = (w & 1) * 64;
    const int wn = (w >> 1) * 64;

    const int srow = lane >> 2;
    const int scol = (lane & 3) * 8;

    const unsigned short* gpb[4];
    unsigned loffb[4];
#pragma unroll
    for (int i = 0; i < 4; ++i) {
        int c = w * 4 + i;
        const unsigned short* pl = (c < 8) ? Bth : Btl;
        int rowg = n0 + (c & 7) * 16 + srow;
        gpb[i] = pl + (size_t)rowg * Kp + scol;
        loffb[i] = 4096 + c * 512;
    }

    facc4 acc[4][4];
    facc4 zero = {0.f, 0.f, 0.f, 0.f};
#pragma unroll
    for (int i = 0; i < 4; ++i)
#pragma unroll
        for (int j = 0; j < 4; ++j) acc[i][j] = zero;

    const int fr = lane & 15;
    const int fq = (lane >> 4) * 8;

    for (int k0 = 0; k0 < Kp; k0 += 32) {
#pragma unroll
        for (int i = 0; i < 4; ++i) {
            load_lds16(gpb[i], &lds[loffb[i]]);
            gpb[i] += 32;
        }
        // A fp32 -> BN affine + relu -> bf16 into LDS (128 rows x 32 k)
#pragma unroll
        for (int i = 0; i < 4; ++i) {
            int idx = tid + i * 256;
            int row = idx >> 3;
            int q4 = idx & 7;
            int rg = min(m0 + row, M - 1);
            int kk = k0 + q4 * 4;
            us4 h;
            if (kk < K) {
                float4 v = *(const float4*)&A[(size_t)rg * K + kk];
                float4 sa = *(const float4*)&abn[kk];
                float4 sb = *(const float4*)&abn[K + kk];
                h.x = f2bf(fmaxf(fmaf(v.x, sa.x, sb.x), 0.f));
                h.y = f2bf(fmaxf(fmaf(v.y, sa.y, sb.y), 0.f));
                h.z = f2bf(fmaxf(fmaf(v.z, sa.z, sb.z), 0.f));
                h.w = f2bf(fmaxf(fmaf(v.w, sa.w, sb.w), 0.f));
            } else {
                h.x = 0; h.y = 0; h.z = 0; h.w = 0;
            }
            *(us4*)&lds[row * 32 + q4 * 4] = h;
        }
        __syncthreads();

        bfrag8 ah[4], bh[4], bl[4];
#pragma unroll
        for (int t = 0; t < 4; ++t) {
            int ar = wm + t * 16 + fr;
            ah[t] = *(const bfrag8*)&lds[ar * 32 + fq];
            int br = wn + t * 16 + fr;
            bh[t] = *(const bfrag8*)&lds[4096 + br * 32 + fq];
            bl[t] = *(const bfrag8*)&lds[8192 + br * 32 + fq];
        }
#pragma unroll
        for (int i = 0; i < 4; ++i)
#pragma unroll
            for (int j = 0; j < 4; ++j) {
                acc[i][j] = MFMA16(ah[i], bh[j], acc[i][j]);
                acc[i][j] = MFMA16(ah[i], bl[j], acc[i][j]);
            }
        __syncthreads();
    }

#pragma unroll
    for (int i = 0; i < 4; ++i)
#pragma unroll
        for (int j = 0; j < 4; ++j) {
            int col = n0 + wn + j * 16 + (lane & 15);
            if (col >= N) continue;
            float bv = bias[col];
#pragma unroll
            for (int r = 0; r < 4; ++r) {
                int row = m0 + wm + i * 16 + (lane >> 4) * 4 + r;
                if (row < M)
                    C[(size_t)row * N + col] = acc[i][j][r] + bv;
            }
        }

    if (stats != nullptr) {
#pragma unroll
        for (int j = 0; j < 4; ++j) {
            int col = n0 + wn + j * 16 + (lane & 15);
            float cs = 0.f, cq = 0.f;
            if (col < N) {
                float bv = bias[col];
#pragma unroll
                for (int i = 0; i < 4; ++i)
#pragma unroll
                    for (int r = 0; r < 4; ++r) {
                        int row = m0 + wm + i * 16 + (lane >> 4) * 4 + r;
                        if (row < M) {
                            float y = acc[i][j][r] + bv;
                            cs += y;
                            cq = fmaf(y, y, cq);
                        }
                    }
            }
            cs += __shfl_xor(cs, 16, 64); cq += __shfl_xor(cq, 16, 64);
            cs += __shfl_xor(cs, 32, 64); cq += __shfl_xor(cq, 32, 64);
            if ((lane >> 4) == 0 && col < N) {
                atomicAdd(&stats[col], cs);
                atomicAdd(&stats[N + col], cq);
            }
        }
    }
}

// ---------------------------------------------------------------------------
// CSR build (dst-sorted). P[v] = end offset after fill.
// ---------------------------------------------------------------------------
__global__ __launch_bounds__(256) void csr_count(const int* __restrict__ dst, int* __restrict__ P)
{
    int e = blockIdx.x * 256 + threadIdx.x;
    if (e < N_EDGES) atomicAdd(&P[dst[e] + 1], 1);
}

__global__ __launch_bounds__(1024) void csr_scan(int* __restrict__ P)
{
    __shared__ int part[1024];
    const int t = threadIdx.x;
    const int CH = 49;
    int i0 = t * CH;
    int s = 0;
    for (int i = i0; i < i0 + CH; ++i) {
        if (i <= N_NODES) { s += P[i]; P[i] = s; }
    }
    part[t] = s;
    __syncthreads();
    if (t == 0) {
        int run = 0;
        for (int k = 0; k < 1024; ++k) { int tmp = part[k]; part[k] = run; run += tmp; }
    }
    __syncthreads();
    int off = part[t];
    for (int i = i0; i < i0 + CH; ++i) {
        if (i <= N_NODES) P[i] += off;
    }
}

__global__ __launch_bounds__(256) void csr_fill(
    const int* __restrict__ dst, int* __restrict__ P, int* __restrict__ eids)
{
    int e = blockIdx.x * 256 + threadIdx.x;
    if (e < N_EDGES) {
        int pos = atomicAdd(&P[dst[e]], 1);
        eids[pos] = e;
    }
}

// ---------------------------------------------------------------------------
// Re-sort src + edge_feat(->bf16) into CSR edge order. Runs once.
// ---------------------------------------------------------------------------
__global__ __launch_bounds__(256) void edge_pack_bf(
    const int* __restrict__ src, const int* __restrict__ eids,
    const float* __restrict__ edge_feat, int* __restrict__ es,
    unsigned short* __restrict__ efsb)
{
    int j = blockIdx.x * 256 + threadIdx.x;
    if (j >= N_EDGES) return;
    int e = eids[j];
    es[j] = src[e];
    const float* sp = edge_feat + (size_t)e * EFEAT;
    us8 o0, o1;
#pragma unroll
    for (int k = 0; k < 8; ++k) {
        o0[k] = f2bf(sp[k]);
        o1[k] = f2bf(sp[8 + k]);
    }
    *(us8*)&efsb[(size_t)j * EFEAT] = o0;
    *(us8*)&efsb[(size_t)j * EFEAT + 8] = o1;
}

// ---------------------------------------------------------------------------
// Gather aggregation v13: wide-load mapping. Round-6 falsified "bytes-bound":
// FETCH halved (522->269MB) with the fp16 table but duration ROSE and HBM BW
// halved exactly -> the gather is VMEM-INSTRUCTION-RATE bound. Fix: lane owns
// CONTIGUOUS dims (q=0..3: d=4*lane+q via one ushort4 = 512B/wave; q=4:
// d=256+lane via one ushort). Row reads drop 5 -> 2 VMEM instructions.
// Table padded to 320 with zeros so dims>=300 need no masks (eW/eb read as 0,
// relu(0+0)=0, writes 0). dot2 ef@eW transform unchanged (v11-proven).
// ---------------------------------------------------------------------------
__global__ __launch_bounds__(256) void gather_agg7(
    const unsigned short* __restrict__ hnb, const unsigned short* __restrict__ efsb,
    const int* __restrict__ es, const int* __restrict__ P,
    const float* __restrict__ eW, const float* __restrict__ eb,
    unsigned short* __restrict__ aggH)
{
    const int v = blockIdx.x * 4 + (threadIdx.x >> 6);
    if (v >= N_NODES) return;
    const int lane = threadIdx.x & 63;

    // lane-owned dims: q<4 -> d=4*lane+q (0..255); q==4 -> d=256+lane (256..319)
    float acc[5];
    float ebv[5];
    {
        us4 r4 = *(const us4*)&hnb[(size_t)v * HSTRIDE + 4 * lane];
        acc[0] = h2f(r4.x); acc[1] = h2f(r4.y);
        acc[2] = h2f(r4.z); acc[3] = h2f(r4.w);
        acc[4] = h2f(hnb[(size_t)v * HSTRIDE + 256 + lane]);
    }
#if GATHER_DOT2
    unsigned wpk[8][5];   // feature-pair p=(2p,2p+1), owned-dim slot q
#pragma unroll
    for (int q = 0; q < 5; ++q) {
        int d = (q < 4) ? 4 * lane + q : 256 + lane;
        bool dv = d < DIM;
        ebv[q] = dv ? eb[d] : 0.f;
#pragma unroll
        for (int p = 0; p < 8; ++p) {
            unsigned short h0 = dv ? f2bf(eW[(2 * p) * DIM + d]) : (unsigned short)0;
            unsigned short h1 = dv ? f2bf(eW[(2 * p + 1) * DIM + d]) : (unsigned short)0;
            wpk[p][q] = (unsigned)h0 | ((unsigned)h1 << 16);
        }
    }
#else
    float wr[EFEAT][5];
#pragma unroll
    for (int q = 0; q < 5; ++q) {
        int d = (q < 4) ? 4 * lane + q : 256 + lane;
        bool dv = d < DIM;
        ebv[q] = dv ? eb[d] : 0.f;
#pragma unroll
        for (int k = 0; k < EFEAT; ++k)
            wr[k][q] = dv ? eW[k * DIM + d] : 0.f;
    }
#endif

    const int j0 = (v == 0) ? 0 : P[v - 1];
    const int j1 = P[v];

    int j = j0;
    for (; j + 4 <= j1; j += 4) {
        int s0 = __builtin_amdgcn_readfirstlane(es[j]);
        int s1 = __builtin_amdgcn_readfirstlane(es[j + 1]);
        int s2 = __builtin_amdgcn_readfirstlane(es[j + 2]);
        int s3 = __builtin_amdgcn_readfirstlane(es[j + 3]);
        const unsigned short* __restrict__ h0 = hnb + (size_t)s0 * HSTRIDE;
        const unsigned short* __restrict__ h1 = hnb + (size_t)s1 * HSTRIDE;
        const unsigned short* __restrict__ h2p = hnb + (size_t)s2 * HSTRIDE;
        const unsigned short* __restrict__ h3 = hnb + (size_t)s3 * HSTRIDE;
        us4 r4[4];
        unsigned short r1[4];
        r4[0] = *(const us4*)&h0[4 * lane];  r1[0] = h0[256 + lane];
        r4[1] = *(const us4*)&h1[4 * lane];  r1[1] = h1[256 + lane];
        r4[2] = *(const us4*)&h2p[4 * lane]; r1[2] = h2p[256 + lane];
        r4[3] = *(const us4*)&h3[4 * lane];  r1[3] = h3[256 + lane];
#if GATHER_DOT2
        ui4 pa[4][2];
#pragma unroll
        for (int u = 0; u < 4; ++u) {
            pa[u][0] = *(const ui4*)&efsb[(size_t)(j + u) * EFEAT];
            pa[u][1] = *(const ui4*)&efsb[(size_t)(j + u) * EFEAT + 8];
        }
#pragma unroll
        for (int u = 0; u < 4; ++u) {
            float hv[5];
            hv[0] = h2f(r4[u][0]); hv[1] = h2f(r4[u][1]);
            hv[2] = h2f(r4[u][2]); hv[3] = h2f(r4[u][3]);
            hv[4] = h2f(r1[u]);
#pragma unroll
            for (int q = 0; q < 5; ++q) {
                float he = ebv[q];
                he = dot2bf(pa[u][0][0], wpk[0][q], he);
                he = dot2bf(pa[u][0][1], wpk[1][q], he);
                he = dot2bf(pa[u][0][2], wpk[2][q], he);
                he = dot2bf(pa[u][0][3], wpk[3][q], he);
                he = dot2bf(pa[u][1][0], wpk[4][q], he);
                he = dot2bf(pa[u][1][1], wpk[5][q], he);
                he = dot2bf(pa[u][1][2], wpk[6][q], he);
                he = dot2bf(pa[u][1][3], wpk[7][q], he);
                acc[q] += fmaxf(hv[q] + he, 0.f);
            }
        }
#else
        us8 pk[4][2];
#pragma unroll
        for (int u = 0; u < 4; ++u) {
            pk[u][0] = *(const us8*)&efsb[(size_t)(j + u) * EFEAT];
            pk[u][1] = *(const us8*)&efsb[(size_t)(j + u) * EFEAT + 8];
        }
#pragma unroll
        for (int u = 0; u < 4; ++u) {
            float hv[5];
            hv[0] = h2f(r4[u][0]); hv[1] = h2f(r4[u][1]);
            hv[2] = h2f(r4[u][2]); hv[3] = h2f(r4[u][3]);
            hv[4] = h2f(r1[u]);
            float ef[EFEAT];
#pragma unroll
            for (int k = 0; k < 8; ++k) {
                ef[k] = bf2f(pk[u][0][k]);
                ef[8 + k] = bf2f(pk[u][1][k]);
            }
#pragma unroll
            for (int q = 0; q < 5; ++q) {
                float he = ebv[q];
#pragma unroll
                for (int k = 0; k < EFEAT; ++k) he = fmaf(ef[k], wr[k][q], he);
                acc[q] += fmaxf(hv[q] + he, 0.f);
            }
        }
#endif
    }
    for (; j < j1; ++j) {
        int s = __builtin_amdgcn_readfirstlane(es[j]);
        const unsigned short* __restrict__ hp = hnb + (size_t)s * HSTRIDE;
        us4 r4 = *(const us4*)&hp[4 * lane];
        unsigned short r1 = hp[256 + lane];
        float hv[5];
        hv[0] = h2f(r4.x); hv[1] = h2f(r4.y);
        hv[2] = h2f(r4.z); hv[3] = h2f(r4.w);
        hv[4] = h2f(r1);
#if GATHER_DOT2
        ui4 p0 = *(const ui4*)&efsb[(size_t)j * EFEAT];
        ui4 p1 = *(const ui4*)&efsb[(size_t)j * EFEAT + 8];
#pragma unroll
        for (int q = 0; q < 5; ++q) {
            float he = ebv[q];
            he = dot2bf(p0[0], wpk[0][q], he);
            he = dot2bf(p0[1], wpk[1][q], he);
            he = dot2bf(p0[2], wpk[2][q], he);
            he = dot2bf(p0[3], wpk[3][q], he);
            he = dot2bf(p1[0], wpk[4][q], he);
            he = dot2bf(p1[1], wpk[5][q], he);
            he = dot2bf(p1[2], wpk[6][q], he);
            he = dot2bf(p1[3], wpk[7][q], he);
            acc[q] += fmaxf(hv[q] + he, 0.f);
        }
#else
        us8 p0 = *(const us8*)&efsb[(size_t)j * EFEAT];
        us8 p1 = *(const us8*)&efsb[(size_t)j * EFEAT + 8];
        float ef[EFEAT];
#pragma unroll
        for (int k = 0; k < 8; ++k) {
            ef[k] = bf2f(p0[k]);
            ef[8 + k] = bf2f(p1[k]);
        }
#pragma unroll
        for (int q = 0; q < 5; ++q) {
            float he = ebv[q];
#pragma unroll
            for (int k = 0; k < EFEAT; ++k) he = fmaf(ef[k], wr[k][q], he);
            acc[q] += fmaxf(hv[q] + he, 0.f);
        }
#endif
    }

    // write: contiguous us4 (dims 4*lane..4*lane+3) + ushort (256+lane).
    // dims>=300 hold 0 by construction (pad-zero table + zero weights).
    {
        us4 o;
        o.x = f2bf(acc[0]); o.y = f2bf(acc[1]);
        o.z = f2bf(acc[2]); o.w = f2bf(acc[3]);
        *(us4*)&aggH[(size_t)v * 320 + 4 * lane] = o;
        aggH[(size_t)v * 320 + 256 + lane] = f2bf(acc[4]);
    }
}

// ---------------------------------------------------------------------------
// BN finalize + apply (apply writes the fp16 node table for the next gather)
// ---------------------------------------------------------------------------
__global__ __launch_bounds__(256) void bn_finalize(
    const float* __restrict__ stats, const float* __restrict__ g,
    const float* __restrict__ beta, float* __restrict__ ab, int C)
{
    int c = blockIdx.x * 256 + threadIdx.x;
    if (c >= C) return;
    const float invN = 1.f / (float)N_NODES;
    float m = stats[c] * invN;
    float v = stats[C + c] * invN - m * m;
    float a = g[c] * rsqrtf(v + BN_EPS);
    ab[c] = a;
    ab[C + c] = beta[c] - m * a;
}

// y = relu(x*a+b) -> fp16 rows [N][HSTRIDE], zero pad 300..319
__global__ __launch_bounds__(256) void bn_apply_h(
    const float* __restrict__ x, const float* __restrict__ ab,
    unsigned short* __restrict__ hnb)
{
    int i = blockIdx.x * 256 + threadIdx.x;
    if (i >= N_NODES * 80) return;
    int row = i / 80;
    int q = i - row * 80;
    int c = 4 * q;
    us4 o;
    if (q < 75) {
        float4 v = ((const float4*)x)[row * 75 + q];
        const float* a = ab + c;
        const float* bb = ab + DIM + c;
        o.x = f2h(fmaxf(fmaf(v.x, a[0], bb[0]), 0.f));
        o.y = f2h(fmaxf(fmaf(v.y, a[1], bb[1]), 0.f));
        o.z = f2h(fmaxf(fmaf(v.z, a[2], bb[2]), 0.f));
        o.w = f2h(fmaxf(fmaf(v.w, a[3], bb[3]), 0.f));
    } else {
        o.x = 0; o.y = 0; o.z = 0; o.w = 0;
    }
    *(us4*)&hnb[(size_t)row * HSTRIDE + c] = o;
}

// ---------------------------------------------------------------------------
// Mean pooling fused with last BN affine: hg = a*mean(h2)+b.
// ---------------------------------------------------------------------------
__global__ __launch_bounds__(256) void pool_seg_bn(
    const float* __restrict__ h2, const int* __restrict__ gid,
    const float* __restrict__ ab, float* __restrict__ hg)
{
    const int g = blockIdx.x;
    int lo = 0, hi = N_NODES;
    while (lo < hi) { int mid = (lo + hi) >> 1; if (gid[mid] < g) lo = mid + 1; else hi = mid; }
    int lo2 = lo, hi2 = N_NODES;
    while (lo2 < hi2) { int mid = (lo2 + hi2) >> 1; if (gid[mid] < g + 1) lo2 = mid + 1; else hi2 = mid; }
    const float inv = 1.f / fmaxf((float)(lo2 - lo), 1.f);
    for (int d = threadIdx.x; d < DIM; d += 256) {
        float s = 0.f;
        for (int r = lo; r < lo2; ++r) s += h2[(size_t)r * DIM + d];
        hg[(size_t)g * DIM + d] = fmaf(s * inv, ab[d], ab[DIM + d]);
    }
}

// fp32 tiled sgemm for the tiny prediction head
#define TS 64
#define BK 16
#define ASP 68

__global__ __launch_bounds__(256) void sgemm_bias(
    const float* __restrict__ A, const float* __restrict__ B,
    const float* __restrict__ bias, float* __restrict__ C,
    int M, int Ncol, int K)
{
    __shared__ float As[BK][ASP];
    __shared__ float Bs[BK][TS];
    const int tid = threadIdx.x;
    const int bm = blockIdx.x * TS;
    const int bn = blockIdx.y * TS;
    const int tm = (tid >> 4) * 4;
    const int tn = (tid & 15) * 4;
    float acc[4][4] = {};

    for (int k0 = 0; k0 < K; k0 += BK) {
#pragma unroll
        for (int i = 0; i < 4; ++i) {
            int idx = tid + i * 256;
            int m = idx >> 4;
            int k = idx & 15;
            int row = bm + m, kk = k0 + k;
            float v = 0.f;
            if (row < M && kk < K) v = A[(size_t)row * K + kk];
            As[k][m] = v;
        }
#pragma unroll
        for (int i = 0; i < 4; ++i) {
            int idx = tid + i * 256;
            int k = idx >> 6;
            int n = idx & 63;
            int col = bn + n, kk = k0 + k;
            float v = 0.f;
            if (col < Ncol && kk < K) v = B[(size_t)kk * Ncol + col];
            Bs[k][n] = v;
        }
        __syncthreads();
#pragma unroll
        for (int k = 0; k < BK; ++k) {
            float4 av = *(const float4*)&As[k][tm];
            float4 bv = *(const float4*)&Bs[k][tn];
            float a4[4] = {av.x, av.y, av.z, av.w};
            float b4[4] = {bv.x, bv.y, bv.z, bv.w};
#pragma unroll
            for (int i = 0; i < 4; ++i)
#pragma unroll
                for (int j = 0; j < 4; ++j)
                    acc[i][j] = fmaf(a4[i], b4[j], acc[i][j]);
        }
        __syncthreads();
    }

#pragma unroll
    for (int i = 0; i < 4; ++i) {
        int row = bm + tm + i;
        if (row >= M) continue;
#pragma unroll
        for (int j = 0; j < 4; ++j) {
            int col = bn + tn + j;
            if (col < Ncol)
                C[(size_t)row * Ncol + col] = acc[i][j] + bias[col];
        }
    }
}

// ---------------------------------------------------------------------------
extern "C" void kernel_launch(void* const* d_in, const int* in_sizes, int n_in,
                              void* d_out, int out_size, void* d_ws, size_t ws_size,
                              hipStream_t stream)
{
    const float* node_feat = (const float*)d_in[0];
    const float* edge_feat = (const float*)d_in[1];
    const int*   src       = (const int*)d_in[2];
    const int*   dst       = (const int*)d_in[3];
    const int*   gid       = (const int*)d_in[4];
    const float* node_W = (const float*)d_in[6];
    const float* node_b = (const float*)d_in[7];
    const float* edge_W = (const float*)d_in[8];
    const float* edge_b = (const float*)d_in[9];
    const float* W1  = (const float*)d_in[10];
    const float* b1  = (const float*)d_in[11];
    const float* g1  = (const float*)d_in[12];
    const float* be1 = (const float*)d_in[13];
    const float* W2  = (const float*)d_in[14];
    const float* b2  = (const float*)d_in[15];
    const float* g2  = (const float*)d_in[16];
    const float* be2 = (const float*)d_in[17];
    const float* pred_W = (const float*)d_in[18];
    const float* pred_b = (const float*)d_in[19];
    float* out = (float*)d_out;

    // ---- workspace layout (bytes), total < 248.73 MB (r9-proven) ----
    // hnb (fp16 node table, 32MB) aliases the head of x1: lifetime is
    // bn_apply_h(l) [or toh_row] -> gather(l+1); x1 is dead in that window
    // and gemm_pp(l+1) overwrites it only after gather(l+1) completes.
    char* base = (char*)d_ws;
    float* hn            = (float*)(base + 0);                 // 60,000,000
    float* h2            = hn;                                 // in-place
    float* x1            = (float*)(base + 60000000);          // 120,000,000
    unsigned short* nfH  = (unsigned short*)x1;                // alias (encoder only)
    unsigned short* hnb  = (unsigned short*)x1;                // alias (gather rows)
    unsigned short* aggH = (unsigned short*)(base + 180000000);// 32,000,000
    int*   es            = (int*)(base + 212000000);           // 3,200,000
    unsigned short* efsb = (unsigned short*)(base + 215200000);// 25,600,000
    unsigned short* wtH  = (unsigned short*)(base + 244000000);
    unsigned short* wtL  = (unsigned short*)(base + 244500000);
    int*   eids          = (int*)(base + 245000000);           // 3,200,000
    int*   P             = (int*)(base + 248200000);           // 200,004
    float* stats         = (float*)(base + 248400016);
    float* ab            = (float*)(base + 248407216);
    float* hg            = (float*)(base + 248414416);         // 307,200
    float* stats2        = stats + 1200;
    float* ab2           = ab + 1200;

    dim3 blk(256);

    // ---- node encoder: hn = node_feat @ node_W + node_b ----
    tobf4<<<dim3((N_NODES * NFEAT / 4 + 255) / 256), blk, 0, stream>>>(
        node_feat, nfH, N_NODES * NFEAT / 4);
    conv_wt<<<dim3((384 * 128 + 255) / 256), blk, 0, stream>>>(
        node_W, wtH, wtL, NFEAT, DIM, 128, 384);
    gemm_pp<<<dim3(3, 391), blk, 0, stream>>>(
        nfH, wtH, wtL, node_b, hn, N_NODES, DIM, 128, nullptr);
    // fp16 row table for the gather (overwrites nfH — dead after gemm)
    toh_row<<<dim3((N_NODES * 80 + 255) / 256), blk, 0, stream>>>(hn, hnb);

    // ---- CSR by dst + packed edge streams (layer-invariant, run once) ----
    hipMemsetAsync(P, 0, (N_NODES + 1) * sizeof(int), stream);
    csr_count<<<dim3((N_EDGES + 255) / 256), blk, 0, stream>>>(dst, P);
    csr_scan<<<dim3(1), dim3(1024), 0, stream>>>(P);
    csr_fill<<<dim3((N_EDGES + 255) / 256), blk, 0, stream>>>(dst, P, eids);
    edge_pack_bf<<<dim3((N_EDGES + 255) / 256), blk, 0, stream>>>(
        src, eids, edge_feat, es, efsb);

    for (int l = 0; l < N_LAYERS; ++l) {
        // aggH = bf16(hnb + sum relu(hnb[src] + he))  [N][320]
        gather_agg7<<<dim3((N_NODES + 3) / 4), blk, 0, stream>>>(
            hnb, efsb, es, P,
            edge_W + (size_t)l * EFEAT * DIM, edge_b + (size_t)l * DIM, aggH);

        hipMemsetAsync(stats, 0, 1800 * sizeof(float), stream);

        // x1 = agg @ W1 + b1   [N, 600]  (+ BN1 stats in epilogue)
        conv_wt<<<dim3((640 * 320 + 255) / 256), blk, 0, stream>>>(
            W1 + (size_t)l * DIM * 2 * DIM, wtH, wtL, DIM, 2 * DIM, 320, 640);
        gemm_pp<<<dim3(5, 391), blk, 0, stream>>>(
            aggH, wtH, wtL, b1 + (size_t)l * 2 * DIM, x1,
            N_NODES, 2 * DIM, 320, stats);
        bn_finalize<<<dim3(3), blk, 0, stream>>>(
            stats, g1 + (size_t)l * 2 * DIM, be1 + (size_t)l * 2 * DIM, ab, 2 * DIM);

        // h2(=hn) = relu(bn1(x1)) @ W2 + b2  (BN1 fused in staging; BN2 stats)
        conv_wt<<<dim3((384 * 608 + 255) / 256), blk, 0, stream>>>(
            W2 + (size_t)l * 2 * DIM * DIM, wtH, wtL, 2 * DIM, DIM, 608, 384);
        gemm_af<<<dim3(3, 391), blk, 0, stream>>>(
            x1, wtH, wtL, b2 + (size_t)l * DIM, h2, N_NODES, DIM, 2 * DIM, 608,
            ab, stats2);
        bn_finalize<<<dim3(2), blk, 0, stream>>>(
            stats2, g2 + (size_t)l * DIM, be2 + (size_t)l * DIM, ab2, DIM);

        // next-layer node table: hnb = fp16(relu(bn2(h2))) — last layer pools
        if (l < N_LAYERS - 1)
            bn_apply_h<<<dim3((N_NODES * 80 + 255) / 256), blk, 0, stream>>>(
                h2, ab2, hnb);
    }

    // ---- mean pool with fused last-BN affine + head ----
    pool_seg_bn<<<dim3(N_GRAPHS), blk, 0, stream>>>(h2, gid, ab2, hg);
    sgemm_bias<<<dim3((N_GRAPHS + 63) / 64, (OUTD + 63) / 64), blk, 0, stream>>>(
        hg, pred_W, pred_b, out, N_GRAPHS, OUTD, DIM);
}

// Round 8
// 1849.900 us; speedup vs baseline: 1.1030x; 1.0363x over previous
//
#include <hip/hip_runtime.h>
#include <hip/hip_fp16.h>

#define N_NODES 50000
#define N_EDGES 800000
#define N_GRAPHS 256
#define N_LAYERS 3
#define DIM 300
#define NFEAT 128
#define EFEAT 16
#define OUTD 128
#define BN_EPS 1e-5f
#define HSTRIDE 320   // fp16 node-row stride (300 + zero pad to 320)

typedef __attribute__((ext_vector_type(8))) _Float16 hfrag8; // 8 fp16 = 4 VGPR (MFMA A/B)
typedef __attribute__((ext_vector_type(4))) float facc4;     // MFMA C/D
typedef __attribute__((ext_vector_type(4))) unsigned short us4;
typedef __attribute__((ext_vector_type(8))) unsigned short us8;
typedef __attribute__((ext_vector_type(4))) unsigned int ui4;

// ---------------- bf16 helpers (RNE) ----------------
__device__ __forceinline__ unsigned short f2bf(float f) {
    unsigned u = __float_as_uint(f);
    unsigned r = ((u >> 16) & 1u) + 0x7fffu;
    return (unsigned short)((u + r) >> 16);
}
__device__ __forceinline__ float bf2f(unsigned short h) {
    return __uint_as_float(((unsigned)h) << 16);
}
// fp16 pack/unpack (single v_cvt each)
__device__ __forceinline__ unsigned short f2h(float f) {
    return __half_as_ushort(__float2half(f));
}
__device__ __forceinline__ float h2f(unsigned short u) {
    return __half2float(__ushort_as_half(u));
}

// v_dot2_f32_bf16: 2 bf16 MACs per instruction (gather ef@eW). Guarded.
#if __has_builtin(__builtin_amdgcn_fdot2_f32_bf16)
#define GATHER_DOT2 1
typedef __attribute__((ext_vector_type(2))) __bf16 bf16x2_t;
__device__ __forceinline__ float dot2bf(unsigned a, unsigned b, float c) {
    return __builtin_amdgcn_fdot2_f32_bf16(
        __builtin_bit_cast(bf16x2_t, a), __builtin_bit_cast(bf16x2_t, b), c, false);
}
#else
#define GATHER_DOT2 0
#endif

// async global->LDS, 16B per lane. LDS dest = uniform base + lane*16 (HW rule).
__device__ __forceinline__ void load_lds16(const void* gsrc, void* ldsdst) {
    __builtin_amdgcn_global_load_lds(
        (const __attribute__((address_space(1))) unsigned int*)gsrc,
        (__attribute__((address_space(3))) unsigned int*)ldsdst,
        16, 0, 0);
}

// fp16 MFMA single-pass (round-8 change): A bf16 was the 2^-9 error floor, so
// hi/lo bf16 B (2 MFMA/tile) bought nothing. fp16 A x fp16 B in ONE MFMA is
// both faster (half the MFMA, -1/3 staged bytes) and more accurate (2^-11).
#define MFMAH(a, b, c) __builtin_amdgcn_mfma_f32_16x16x32_f16(a, b, c, 0, 0, 0)

// ---------------------------------------------------------------------------
// fp32 -> fp16, vectorized (encoder A operand)
// ---------------------------------------------------------------------------
__global__ __launch_bounds__(256) void toh4(
    const float* __restrict__ x, unsigned short* __restrict__ H, int n4)
{
    int i = blockIdx.x * 256 + threadIdx.x;
    if (i >= n4) return;
    float4 v = ((const float4*)x)[i];
    us4 h;
    h.x = f2h(v.x); h.y = f2h(v.y); h.z = f2h(v.z); h.w = f2h(v.w);
    ((us4*)H)[i] = h;
}

// ---------------------------------------------------------------------------
// hn fp32 [N][300] -> fp16 row table hnb [N][320] (zero pad 300..319)
// ---------------------------------------------------------------------------
__global__ __launch_bounds__(256) void toh_row(
    const float* __restrict__ hn, unsigned short* __restrict__ hnb)
{
    int i = blockIdx.x * 256 + threadIdx.x;
    if (i >= N_NODES * 80) return;
    int row = i / 80;
    int q = i - row * 80;
    us4 o;
    if (q < 75) {
        float4 v = *(const float4*)&hn[(size_t)row * DIM + 4 * q];
        o.x = f2h(v.x); o.y = f2h(v.y); o.z = f2h(v.z); o.w = f2h(v.w);
    } else {
        o.x = 0; o.y = 0; o.z = 0; o.w = 0;
    }
    *(us4*)&hnb[(size_t)row * HSTRIDE + 4 * q] = o;
}

// ---------------------------------------------------------------------------
// weight conversion: W fp32 [K][N] -> transposed padded fp16 plane [Np][Kp]
// ---------------------------------------------------------------------------
__global__ __launch_bounds__(256) void conv_wt(
    const float* __restrict__ W, unsigned short* __restrict__ H,
    int K, int N, int Kp, int Np)
{
    int idx = blockIdx.x * 256 + threadIdx.x;
    if (idx >= Np * Kp) return;
    int n = idx / Kp;
    int k = idx - n * Kp;
    float v = (n < N && k < K) ? W[(size_t)k * N + n] : 0.f;
    H[idx] = f2h(v);
}

// ---------------------------------------------------------------------------
// fp16 MFMA GEMM: A fp16 [M][Kp]; B transposed fp16 plane [Np][Kp].
// 1 MFMA/tile (fp16 both sides). Block 128x128, BK=32, 4 waves 2x2.
// GRID: blockIdx.x = N-block (fast-varying) -> A L2 reuse. LDS 16KB: A | B.
// Optional column-stat epilogue (BN).
// ---------------------------------------------------------------------------
__global__ __launch_bounds__(256, 2) void gemm_pp(
    const unsigned short* __restrict__ Ah, const unsigned short* __restrict__ Bt,
    const float* __restrict__ bias, float* __restrict__ C,
    int M, int N, int Kp, float* __restrict__ stats)
{
    __shared__ unsigned short lds[8192];   // 16 KB: A(0..4095) | B(4096..8191)
    const int tid = threadIdx.x;
    const int lane = tid & 63;
    const int w = tid >> 6;
    const int m0 = blockIdx.y * 128;
    const int n0 = blockIdx.x * 128;
    const int wm = (w & 1) * 64;
    const int wn = (w >> 1) * 64;

    const int srow = lane >> 2;
    const int scol = (lane & 3) * 8;

    const unsigned short* gp[4];
    unsigned loff[4];
#pragma unroll
    for (int i = 0; i < 4; ++i) {
        int c = w * 4 + i;                 // 0..7 A rows, 8..15 B rows
        const unsigned short* pl = (c < 8) ? Ah : Bt;
        int rowg;
        if (c < 8) {
            rowg = m0 + (c & 7) * 16 + srow;
            rowg = min(rowg, M - 1);
        } else {
            rowg = n0 + (c & 7) * 16 + srow;
        }
        gp[i] = pl + (size_t)rowg * Kp + scol;
        loff[i] = c * 512;
    }

    facc4 acc[4][4];
    facc4 zero = {0.f, 0.f, 0.f, 0.f};
#pragma unroll
    for (int i = 0; i < 4; ++i)
#pragma unroll
        for (int j = 0; j < 4; ++j) acc[i][j] = zero;

    const int fr = lane & 15;
    const int fq = (lane >> 4) * 8;

    for (int k0 = 0; k0 < Kp; k0 += 32) {
#pragma unroll
        for (int i = 0; i < 4; ++i) {
            load_lds16(gp[i], &lds[loff[i]]);
            gp[i] += 32;
        }
        __syncthreads();

        hfrag8 ah[4], bh[4];
#pragma unroll
        for (int t = 0; t < 4; ++t) {
            int ar = wm + t * 16 + fr;
            ah[t] = *(const hfrag8*)&lds[ar * 32 + fq];
            int br = wn + t * 16 + fr;
            bh[t] = *(const hfrag8*)&lds[4096 + br * 32 + fq];
        }
#pragma unroll
        for (int i = 0; i < 4; ++i)
#pragma unroll
            for (int j = 0; j < 4; ++j)
                acc[i][j] = MFMAH(ah[i], bh[j], acc[i][j]);
        __syncthreads();
    }

    // epilogue: C/D layout col=lane&15, row=(lane>>4)*4+reg
#pragma unroll
    for (int i = 0; i < 4; ++i)
#pragma unroll
        for (int j = 0; j < 4; ++j) {
            int col = n0 + wn + j * 16 + (lane & 15);
            if (col >= N) continue;
            float bv = bias[col];
#pragma unroll
            for (int r = 0; r < 4; ++r) {
                int row = m0 + wm + i * 16 + (lane >> 4) * 4 + r;
                if (row < M)
                    C[(size_t)row * N + col] = acc[i][j][r] + bv;
            }
        }

    if (stats != nullptr) {
#pragma unroll
        for (int j = 0; j < 4; ++j) {
            int col = n0 + wn + j * 16 + (lane & 15);
            float cs = 0.f, cq = 0.f;
            if (col < N) {
                float bv = bias[col];
#pragma unroll
                for (int i = 0; i < 4; ++i)
#pragma unroll
                    for (int r = 0; r < 4; ++r) {
                        int row = m0 + wm + i * 16 + (lane >> 4) * 4 + r;
                        if (row < M) {
                            float y = acc[i][j][r] + bv;
                            cs += y;
                            cq = fmaf(y, y, cq);
                        }
                    }
            }
            cs += __shfl_xor(cs, 16, 64); cq += __shfl_xor(cq, 16, 64);
            cs += __shfl_xor(cs, 32, 64); cq += __shfl_xor(cq, 32, 64);
            if ((lane >> 4) == 0 && col < N) {
                atomicAdd(&stats[col], cs);
                atomicAdd(&stats[N + col], cq);
            }
        }
    }
}

// ---------------------------------------------------------------------------
// fp16 MFMA GEMM, A fp32 with fused BN-affine+ReLU applied during staging
// (abn = [a K | b K], y = relu(x*a+b)) -> fp16. Column-stat epilogue for BN2.
// ---------------------------------------------------------------------------
__global__ __launch_bounds__(256, 2) void gemm_af(
    const float* __restrict__ A, const unsigned short* __restrict__ Bt,
    const float* __restrict__ bias, float* __restrict__ C,
    int M, int N, int K, int Kp,
    const float* __restrict__ abn, float* __restrict__ stats)
{
    __shared__ unsigned short lds[8192];   // 16 KB: A(0..4095) | B(4096..8191)
    const int tid = threadIdx.x;
    const int lane = tid & 63;
    const int w = tid >> 6;
    const int m0 = blockIdx.y * 128;
    const int n0 = blockIdx.x * 128;
    const int wm = (w & 1) * 64;
    const int wn = (w >> 1) * 64;

    const int srow = lane >> 2;
    const int scol = (lane & 3) * 8;

    const unsigned short* gpb[2];
    unsigned loffb[2];
#pragma unroll
    for (int i = 0; i < 2; ++i) {
        int c = w * 2 + i;                 // 0..7 B rows
        int rowg = n0 + c * 16 + srow;
        gpb[i] = Bt + (size_t)rowg * Kp + scol;
        loffb[i] = 4096 + c * 512;
    }

    facc4 acc[4][4];
    facc4 zero = {0.f, 0.f, 0.f, 0.f};
#pragma unroll
    for (int i = 0; i < 4; ++i)
#pragma unroll
        for (int j = 0; j < 4; ++j) acc[i][j] = zero;

    const int fr = lane & 15;
    const int fq = (lane >> 4) * 8;

    for (int k0 = 0; k0 < Kp; k0 += 32) {
#pragma unroll
        for (int i = 0; i < 2; ++i) {
            load_lds16(gpb[i], &lds[loffb[i]]);
            gpb[i] += 32;
        }
        // A fp32 -> BN affine + relu -> fp16 into LDS (128 rows x 32 k)
#pragma unroll
        for (int i = 0; i < 4; ++i) {
            int idx = tid + i * 256;
            int row = idx >> 3;
            int q4 = idx & 7;
            int rg = min(m0 + row, M - 1);
            int kk = k0 + q4 * 4;
            us4 h;
            if (kk < K) {
                float4 v = *(const float4*)&A[(size_t)rg * K + kk];
                float4 sa = *(const float4*)&abn[kk];
                float4 sb = *(const float4*)&abn[K + kk];
                h.x = f2h(fmaxf(fmaf(v.x, sa.x, sb.x), 0.f));
                h.y = f2h(fmaxf(fmaf(v.y, sa.y, sb.y), 0.f));
                h.z = f2h(fmaxf(fmaf(v.z, sa.z, sb.z), 0.f));
                h.w = f2h(fmaxf(fmaf(v.w, sa.w, sb.w), 0.f));
            } else {
                h.x = 0; h.y = 0; h.z = 0; h.w = 0;
            }
            *(us4*)&lds[row * 32 + q4 * 4] = h;
        }
        __syncthreads();

        hfrag8 ah[4], bh[4];
#pragma unroll
        for (int t = 0; t < 4; ++t) {
            int ar = wm + t * 16 + fr;
            ah[t] = *(const hfrag8*)&lds[ar * 32 + fq];
            int br = wn + t * 16 + fr;
            bh[t] = *(const hfrag8*)&lds[4096 + br * 32 + fq];
        }
#pragma unroll
        for (int i = 0; i < 4; ++i)
#pragma unroll
            for (int j = 0; j < 4; ++j)
                acc[i][j] = MFMAH(ah[i], bh[j], acc[i][j]);
        __syncthreads();
    }

#pragma unroll
    for (int i = 0; i < 4; ++i)
#pragma unroll
        for (int j = 0; j < 4; ++j) {
            int col = n0 + wn + j * 16 + (lane & 15);
            if (col >= N) continue;
            float bv = bias[col];
#pragma unroll
            for (int r = 0; r < 4; ++r) {
                int row = m0 + wm + i * 16 + (lane >> 4) * 4 + r;
                if (row < M)
                    C[(size_t)row * N + col] = acc[i][j][r] + bv;
            }
        }

    if (stats != nullptr) {
#pragma unroll
        for (int j = 0; j < 4; ++j) {
            int col = n0 + wn + j * 16 + (lane & 15);
            float cs = 0.f, cq = 0.f;
            if (col < N) {
                float bv = bias[col];
#pragma unroll
                for (int i = 0; i < 4; ++i)
#pragma unroll
                    for (int r = 0; r < 4; ++r) {
                        int row = m0 + wm + i * 16 + (lane >> 4) * 4 + r;
                        if (row < M) {
                            float y = acc[i][j][r] + bv;
                            cs += y;
                            cq = fmaf(y, y, cq);
                        }
                    }
            }
            cs += __shfl_xor(cs, 16, 64); cq += __shfl_xor(cq, 16, 64);
            cs += __shfl_xor(cs, 32, 64); cq += __shfl_xor(cq, 32, 64);
            if ((lane >> 4) == 0 && col < N) {
                atomicAdd(&stats[col], cs);
                atomicAdd(&stats[N + col], cq);
            }
        }
    }
}

// ---------------------------------------------------------------------------
// CSR build (dst-sorted). P[v] = end offset after fill.
// ---------------------------------------------------------------------------
__global__ __launch_bounds__(256) void csr_count(const int* __restrict__ dst, int* __restrict__ P)
{
    int e = blockIdx.x * 256 + threadIdx.x;
    if (e < N_EDGES) atomicAdd(&P[dst[e] + 1], 1);
}

__global__ __launch_bounds__(1024) void csr_scan(int* __restrict__ P)
{
    __shared__ int part[1024];
    const int t = threadIdx.x;
    const int CH = 49;
    int i0 = t * CH;
    int s = 0;
    for (int i = i0; i < i0 + CH; ++i) {
        if (i <= N_NODES) { s += P[i]; P[i] = s; }
    }
    part[t] = s;
    __syncthreads();
    if (t == 0) {
        int run = 0;
        for (int k = 0; k < 1024; ++k) { int tmp = part[k]; part[k] = run; run += tmp; }
    }
    __syncthreads();
    int off = part[t];
    for (int i = i0; i < i0 + CH; ++i) {
        if (i <= N_NODES) P[i] += off;
    }
}

__global__ __launch_bounds__(256) void csr_fill(
    const int* __restrict__ dst, int* __restrict__ P, int* __restrict__ eids)
{
    int e = blockIdx.x * 256 + threadIdx.x;
    if (e < N_EDGES) {
        int pos = atomicAdd(&P[dst[e]], 1);
        eids[pos] = e;
    }
}

// ---------------------------------------------------------------------------
// Re-sort src + edge_feat(->bf16) into CSR edge order. Runs once.
// ---------------------------------------------------------------------------
__global__ __launch_bounds__(256) void edge_pack_bf(
    const int* __restrict__ src, const int* __restrict__ eids,
    const float* __restrict__ edge_feat, int* __restrict__ es,
    unsigned short* __restrict__ efsb)
{
    int j = blockIdx.x * 256 + threadIdx.x;
    if (j >= N_EDGES) return;
    int e = eids[j];
    es[j] = src[e];
    const float* sp = edge_feat + (size_t)e * EFEAT;
    us8 o0, o1;
#pragma unroll
    for (int k = 0; k < 8; ++k) {
        o0[k] = f2bf(sp[k]);
        o1[k] = f2bf(sp[8 + k]);
    }
    *(us8*)&efsb[(size_t)j * EFEAT] = o0;
    *(us8*)&efsb[(size_t)j * EFEAT + 8] = o1;
}

// ---------------------------------------------------------------------------
// Gather aggregation v13 (195us/layer proven): wide-load lane->dim mapping
// (q<4: d=4*lane+q via ushort4; q==4: d=256+lane), fp16 row table, dot2
// ef@eW. Output aggH now fp16 (feeds the fp16 MFMA GEMM directly).
// ---------------------------------------------------------------------------
__global__ __launch_bounds__(256) void gather_agg7(
    const unsigned short* __restrict__ hnb, const unsigned short* __restrict__ efsb,
    const int* __restrict__ es, const int* __restrict__ P,
    const float* __restrict__ eW, const float* __restrict__ eb,
    unsigned short* __restrict__ aggH)
{
    const int v = blockIdx.x * 4 + (threadIdx.x >> 6);
    if (v >= N_NODES) return;
    const int lane = threadIdx.x & 63;

    // lane-owned dims: q<4 -> d=4*lane+q (0..255); q==4 -> d=256+lane (256..319)
    float acc[5];
    float ebv[5];
    {
        us4 r4 = *(const us4*)&hnb[(size_t)v * HSTRIDE + 4 * lane];
        acc[0] = h2f(r4.x); acc[1] = h2f(r4.y);
        acc[2] = h2f(r4.z); acc[3] = h2f(r4.w);
        acc[4] = h2f(hnb[(size_t)v * HSTRIDE + 256 + lane]);
    }
#if GATHER_DOT2
    unsigned wpk[8][5];   // feature-pair p=(2p,2p+1), owned-dim slot q
#pragma unroll
    for (int q = 0; q < 5; ++q) {
        int d = (q < 4) ? 4 * lane + q : 256 + lane;
        bool dv = d < DIM;
        ebv[q] = dv ? eb[d] : 0.f;
#pragma unroll
        for (int p = 0; p < 8; ++p) {
            unsigned short h0 = dv ? f2bf(eW[(2 * p) * DIM + d]) : (unsigned short)0;
            unsigned short h1 = dv ? f2bf(eW[(2 * p + 1) * DIM + d]) : (unsigned short)0;
            wpk[p][q] = (unsigned)h0 | ((unsigned)h1 << 16);
        }
    }
#else
    float wr[EFEAT][5];
#pragma unroll
    for (int q = 0; q < 5; ++q) {
        int d = (q < 4) ? 4 * lane + q : 256 + lane;
        bool dv = d < DIM;
        ebv[q] = dv ? eb[d] : 0.f;
#pragma unroll
        for (int k = 0; k < EFEAT; ++k)
            wr[k][q] = dv ? eW[k * DIM + d] : 0.f;
    }
#endif

    const int j0 = (v == 0) ? 0 : P[v - 1];
    const int j1 = P[v];

    int j = j0;
    for (; j + 4 <= j1; j += 4) {
        int s0 = __builtin_amdgcn_readfirstlane(es[j]);
        int s1 = __builtin_amdgcn_readfirstlane(es[j + 1]);
        int s2 = __builtin_amdgcn_readfirstlane(es[j + 2]);
        int s3 = __builtin_amdgcn_readfirstlane(es[j + 3]);
        const unsigned short* __restrict__ h0 = hnb + (size_t)s0 * HSTRIDE;
        const unsigned short* __restrict__ h1 = hnb + (size_t)s1 * HSTRIDE;
        const unsigned short* __restrict__ h2p = hnb + (size_t)s2 * HSTRIDE;
        const unsigned short* __restrict__ h3 = hnb + (size_t)s3 * HSTRIDE;
        us4 r4[4];
        unsigned short r1[4];
        r4[0] = *(const us4*)&h0[4 * lane];  r1[0] = h0[256 + lane];
        r4[1] = *(const us4*)&h1[4 * lane];  r1[1] = h1[256 + lane];
        r4[2] = *(const us4*)&h2p[4 * lane]; r1[2] = h2p[256 + lane];
        r4[3] = *(const us4*)&h3[4 * lane];  r1[3] = h3[256 + lane];
#if GATHER_DOT2
        ui4 pa[4][2];
#pragma unroll
        for (int u = 0; u < 4; ++u) {
            pa[u][0] = *(const ui4*)&efsb[(size_t)(j + u) * EFEAT];
            pa[u][1] = *(const ui4*)&efsb[(size_t)(j + u) * EFEAT + 8];
        }
#pragma unroll
        for (int u = 0; u < 4; ++u) {
            float hv[5];
            hv[0] = h2f(r4[u][0]); hv[1] = h2f(r4[u][1]);
            hv[2] = h2f(r4[u][2]); hv[3] = h2f(r4[u][3]);
            hv[4] = h2f(r1[u]);
#pragma unroll
            for (int q = 0; q < 5; ++q) {
                float he = ebv[q];
                he = dot2bf(pa[u][0][0], wpk[0][q], he);
                he = dot2bf(pa[u][0][1], wpk[1][q], he);
                he = dot2bf(pa[u][0][2], wpk[2][q], he);
                he = dot2bf(pa[u][0][3], wpk[3][q], he);
                he = dot2bf(pa[u][1][0], wpk[4][q], he);
                he = dot2bf(pa[u][1][1], wpk[5][q], he);
                he = dot2bf(pa[u][1][2], wpk[6][q], he);
                he = dot2bf(pa[u][1][3], wpk[7][q], he);
                acc[q] += fmaxf(hv[q] + he, 0.f);
            }
        }
#else
        us8 pk[4][2];
#pragma unroll
        for (int u = 0; u < 4; ++u) {
            pk[u][0] = *(const us8*)&efsb[(size_t)(j + u) * EFEAT];
            pk[u][1] = *(const us8*)&efsb[(size_t)(j + u) * EFEAT + 8];
        }
#pragma unroll
        for (int u = 0; u < 4; ++u) {
            float hv[5];
            hv[0] = h2f(r4[u][0]); hv[1] = h2f(r4[u][1]);
            hv[2] = h2f(r4[u][2]); hv[3] = h2f(r4[u][3]);
            hv[4] = h2f(r1[u]);
            float ef[EFEAT];
#pragma unroll
            for (int k = 0; k < 8; ++k) {
                ef[k] = bf2f(pk[u][0][k]);
                ef[8 + k] = bf2f(pk[u][1][k]);
            }
#pragma unroll
            for (int q = 0; q < 5; ++q) {
                float he = ebv[q];
#pragma unroll
                for (int k = 0; k < EFEAT; ++k) he = fmaf(ef[k], wr[k][q], he);
                acc[q] += fmaxf(hv[q] + he, 0.f);
            }
        }
#endif
    }
    for (; j < j1; ++j) {
        int s = __builtin_amdgcn_readfirstlane(es[j]);
        const unsigned short* __restrict__ hp = hnb + (size_t)s * HSTRIDE;
        us4 r4 = *(const us4*)&hp[4 * lane];
        unsigned short r1 = hp[256 + lane];
        float hv[5];
        hv[0] = h2f(r4.x); hv[1] = h2f(r4.y);
        hv[2] = h2f(r4.z); hv[3] = h2f(r4.w);
        hv[4] = h2f(r1);
#if GATHER_DOT2
        ui4 p0 = *(const ui4*)&efsb[(size_t)j * EFEAT];
        ui4 p1 = *(const ui4*)&efsb[(size_t)j * EFEAT + 8];
#pragma unroll
        for (int q = 0; q < 5; ++q) {
            float he = ebv[q];
            he = dot2bf(p0[0], wpk[0][q], he);
            he = dot2bf(p0[1], wpk[1][q], he);
            he = dot2bf(p0[2], wpk[2][q], he);
            he = dot2bf(p0[3], wpk[3][q], he);
            he = dot2bf(p1[0], wpk[4][q], he);
            he = dot2bf(p1[1], wpk[5][q], he);
            he = dot2bf(p1[2], wpk[6][q], he);
            he = dot2bf(p1[3], wpk[7][q], he);
            acc[q] += fmaxf(hv[q] + he, 0.f);
        }
#else
        us8 p0 = *(const us8*)&efsb[(size_t)j * EFEAT];
        us8 p1 = *(const us8*)&efsb[(size_t)j * EFEAT + 8];
        float ef[EFEAT];
#pragma unroll
        for (int k = 0; k < 8; ++k) {
            ef[k] = bf2f(p0[k]);
            ef[8 + k] = bf2f(p1[k]);
        }
#pragma unroll
        for (int q = 0; q < 5; ++q) {
            float he = ebv[q];
#pragma unroll
            for (int k = 0; k < EFEAT; ++k) he = fmaf(ef[k], wr[k][q], he);
            acc[q] += fmaxf(hv[q] + he, 0.f);
        }
#endif
    }

    // write fp16 (GEMM A operand): contiguous us4 + ushort; dims>=300 are 0.
    {
        us4 o;
        o.x = f2h(acc[0]); o.y = f2h(acc[1]);
        o.z = f2h(acc[2]); o.w = f2h(acc[3]);
        *(us4*)&aggH[(size_t)v * 320 + 4 * lane] = o;
        aggH[(size_t)v * 320 + 256 + lane] = f2h(acc[4]);
    }
}

// ---------------------------------------------------------------------------
// BN finalize + apply (apply writes the fp16 node table for the next gather)
// ---------------------------------------------------------------------------
__global__ __launch_bounds__(256) void bn_finalize(
    const float* __restrict__ stats, const float* __restrict__ g,
    const float* __restrict__ beta, float* __restrict__ ab, int C)
{
    int c = blockIdx.x * 256 + threadIdx.x;
    if (c >= C) return;
    const float invN = 1.f / (float)N_NODES;
    float m = stats[c] * invN;
    float v = stats[C + c] * invN - m * m;
    float a = g[c] * rsqrtf(v + BN_EPS);
    ab[c] = a;
    ab[C + c] = beta[c] - m * a;
}

// y = relu(x*a+b) -> fp16 rows [N][HSTRIDE], zero pad 300..319
__global__ __launch_bounds__(256) void bn_apply_h(
    const float* __restrict__ x, const float* __restrict__ ab,
    unsigned short* __restrict__ hnb)
{
    int i = blockIdx.x * 256 + threadIdx.x;
    if (i >= N_NODES * 80) return;
    int row = i / 80;
    int q = i - row * 80;
    int c = 4 * q;
    us4 o;
    if (q < 75) {
        float4 v = ((const float4*)x)[row * 75 + q];
        const float* a = ab + c;
        const float* bb = ab + DIM + c;
        o.x = f2h(fmaxf(fmaf(v.x, a[0], bb[0]), 0.f));
        o.y = f2h(fmaxf(fmaf(v.y, a[1], bb[1]), 0.f));
        o.z = f2h(fmaxf(fmaf(v.z, a[2], bb[2]), 0.f));
        o.w = f2h(fmaxf(fmaf(v.w, a[3], bb[3]), 0.f));
    } else {
        o.x = 0; o.y = 0; o.z = 0; o.w = 0;
    }
    *(us4*)&hnb[(size_t)row * HSTRIDE + c] = o;
}

// ---------------------------------------------------------------------------
// Mean pooling fused with last BN affine: hg = a*mean(h2)+b.
// ---------------------------------------------------------------------------
__global__ __launch_bounds__(256) void pool_seg_bn(
    const float* __restrict__ h2, const int* __restrict__ gid,
    const float* __restrict__ ab, float* __restrict__ hg)
{
    const int g = blockIdx.x;
    int lo = 0, hi = N_NODES;
    while (lo < hi) { int mid = (lo + hi) >> 1; if (gid[mid] < g) lo = mid + 1; else hi = mid; }
    int lo2 = lo, hi2 = N_NODES;
    while (lo2 < hi2) { int mid = (lo2 + hi2) >> 1; if (gid[mid] < g + 1) lo2 = mid + 1; else hi2 = mid; }
    const float inv = 1.f / fmaxf((float)(lo2 - lo), 1.f);
    for (int d = threadIdx.x; d < DIM; d += 256) {
        float s = 0.f;
        for (int r = lo; r < lo2; ++r) s += h2[(size_t)r * DIM + d];
        hg[(size_t)g * DIM + d] = fmaf(s * inv, ab[d], ab[DIM + d]);
    }
}

// fp32 tiled sgemm for the tiny prediction head
#define TS 64
#define BK 16
#define ASP 68

__global__ __launch_bounds__(256) void sgemm_bias(
    const float* __restrict__ A, const float* __restrict__ B,
    const float* __restrict__ bias, float* __restrict__ C,
    int M, int Ncol, int K)
{
    __shared__ float As[BK][ASP];
    __shared__ float Bs[BK][TS];
    const int tid = threadIdx.x;
    const int bm = blockIdx.x * TS;
    const int bn = blockIdx.y * TS;
    const int tm = (tid >> 4) * 4;
    const int tn = (tid & 15) * 4;
    float acc[4][4] = {};

    for (int k0 = 0; k0 < K; k0 += BK) {
#pragma unroll
        for (int i = 0; i < 4; ++i) {
            int idx = tid + i * 256;
            int m = idx >> 4;
            int k = idx & 15;
            int row = bm + m, kk = k0 + k;
            float v = 0.f;
            if (row < M && kk < K) v = A[(size_t)row * K + kk];
            As[k][m] = v;
        }
#pragma unroll
        for (int i = 0; i < 4; ++i) {
            int idx = tid + i * 256;
            int k = idx >> 6;
            int n = idx & 63;
            int col = bn + n, kk = k0 + k;
            float v = 0.f;
            if (col < Ncol && kk < K) v = B[(size_t)kk * Ncol + col];
            Bs[k][n] = v;
        }
        __syncthreads();
#pragma unroll
        for (int k = 0; k < BK; ++k) {
            float4 av = *(const float4*)&As[k][tm];
            float4 bv = *(const float4*)&Bs[k][tn];
            float a4[4] = {av.x, av.y, av.z, av.w};
            float b4[4] = {bv.x, bv.y, bv.z, bv.w};
#pragma unroll
            for (int i = 0; i < 4; ++i)
#pragma unroll
                for (int j = 0; j < 4; ++j)
                    acc[i][j] = fmaf(a4[i], b4[j], acc[i][j]);
        }
        __syncthreads();
    }

#pragma unroll
    for (int i = 0; i < 4; ++i) {
        int row = bm + tm + i;
        if (row >= M) continue;
#pragma unroll
        for (int j = 0; j < 4; ++j) {
            int col = bn + tn + j;
            if (col < Ncol)
                C[(size_t)row * Ncol + col] = acc[i][j] + bias[col];
        }
    }
}

// ---------------------------------------------------------------------------
extern "C" void kernel_launch(void* const* d_in, const int* in_sizes, int n_in,
                              void* d_out, int out_size, void* d_ws, size_t ws_size,
                              hipStream_t stream)
{
    const float* node_feat = (const float*)d_in[0];
    const float* edge_feat = (const float*)d_in[1];
    const int*   src       = (const int*)d_in[2];
    const int*   dst       = (const int*)d_in[3];
    const int*   gid       = (const int*)d_in[4];
    const float* node_W = (const float*)d_in[6];
    const float* node_b = (const float*)d_in[7];
    const float* edge_W = (const float*)d_in[8];
    const float* edge_b = (const float*)d_in[9];
    const float* W1  = (const float*)d_in[10];
    const float* b1  = (const float*)d_in[11];
    const float* g1  = (const float*)d_in[12];
    const float* be1 = (const float*)d_in[13];
    const float* W2  = (const float*)d_in[14];
    const float* b2  = (const float*)d_in[15];
    const float* g2  = (const float*)d_in[16];
    const float* be2 = (const float*)d_in[17];
    const float* pred_W = (const float*)d_in[18];
    const float* pred_b = (const float*)d_in[19];
    float* out = (float*)d_out;

    // ---- workspace layout (bytes), total < 248.73 MB ----
    // hnb (fp16 node table, 32MB) aliases the head of x1: lifetime is
    // bn_apply_h(l) [or toh_row] -> gather(l+1); x1 is dead in that window
    // and gemm_pp(l+1) overwrites it only after gather(l+1) completes.
    char* base = (char*)d_ws;
    float* hn            = (float*)(base + 0);                 // 60,000,000
    float* h2            = hn;                                 // in-place
    float* x1            = (float*)(base + 60000000);          // 120,000,000
    unsigned short* nfH  = (unsigned short*)x1;                // alias (encoder only)
    unsigned short* hnb  = (unsigned short*)x1;                // alias (gather rows)
    unsigned short* aggH = (unsigned short*)(base + 180000000);// 32,000,000 (fp16)
    int*   es            = (int*)(base + 212000000);           // 3,200,000
    unsigned short* efsb = (unsigned short*)(base + 215200000);// 25,600,000
    unsigned short* wtH  = (unsigned short*)(base + 244000000);// <=466,944 (fp16 plane)
    int*   eids          = (int*)(base + 245000000);           // 3,200,000
    int*   P             = (int*)(base + 248200000);           // 200,004
    float* stats         = (float*)(base + 248400016);
    float* ab            = (float*)(base + 248407216);
    float* hg            = (float*)(base + 248414416);         // 307,200
    float* stats2        = stats + 1200;
    float* ab2           = ab + 1200;

    dim3 blk(256);

    // ---- node encoder: hn = node_feat @ node_W + node_b ----
    toh4<<<dim3((N_NODES * NFEAT / 4 + 255) / 256), blk, 0, stream>>>(
        node_feat, nfH, N_NODES * NFEAT / 4);
    conv_wt<<<dim3((384 * 128 + 255) / 256), blk, 0, stream>>>(
        node_W, wtH, NFEAT, DIM, 128, 384);
    gemm_pp<<<dim3(3, 391), blk, 0, stream>>>(
        nfH, wtH, node_b, hn, N_NODES, DIM, 128, nullptr);
    // fp16 row table for the gather (overwrites nfH — dead after gemm)
    toh_row<<<dim3((N_NODES * 80 + 255) / 256), blk, 0, stream>>>(hn, hnb);

    // ---- CSR by dst + packed edge streams (layer-invariant, run once) ----
    hipMemsetAsync(P, 0, (N_NODES + 1) * sizeof(int), stream);
    csr_count<<<dim3((N_EDGES + 255) / 256), blk, 0, stream>>>(dst, P);
    csr_scan<<<dim3(1), dim3(1024), 0, stream>>>(P);
    csr_fill<<<dim3((N_EDGES + 255) / 256), blk, 0, stream>>>(dst, P, eids);
    edge_pack_bf<<<dim3((N_EDGES + 255) / 256), blk, 0, stream>>>(
        src, eids, edge_feat, es, efsb);

    for (int l = 0; l < N_LAYERS; ++l) {
        // aggH = fp16(hnb + sum relu(hnb[src] + he))  [N][320]
        gather_agg7<<<dim3((N_NODES + 3) / 4), blk, 0, stream>>>(
            hnb, efsb, es, P,
            edge_W + (size_t)l * EFEAT * DIM, edge_b + (size_t)l * DIM, aggH);

        hipMemsetAsync(stats, 0, 1800 * sizeof(float), stream);

        // x1 = agg @ W1 + b1   [N, 600]  (+ BN1 stats in epilogue)
        conv_wt<<<dim3((640 * 320 + 255) / 256), blk, 0, stream>>>(
            W1 + (size_t)l * DIM * 2 * DIM, wtH, DIM, 2 * DIM, 320, 640);
        gemm_pp<<<dim3(5, 391), blk, 0, stream>>>(
            aggH, wtH, b1 + (size_t)l * 2 * DIM, x1,
            N_NODES, 2 * DIM, 320, stats);
        bn_finalize<<<dim3(3), blk, 0, stream>>>(
            stats, g1 + (size_t)l * 2 * DIM, be1 + (size_t)l * 2 * DIM, ab, 2 * DIM);

        // h2(=hn) = relu(bn1(x1)) @ W2 + b2  (BN1 fused in staging; BN2 stats)
        conv_wt<<<dim3((384 * 608 + 255) / 256), blk, 0, stream>>>(
            W2 + (size_t)l * 2 * DIM * DIM, wtH, 2 * DIM, DIM, 608, 384);
        gemm_af<<<dim3(3, 391), blk, 0, stream>>>(
            x1, wtH, b2 + (size_t)l * DIM, h2, N_NODES, DIM, 2 * DIM, 608,
            ab, stats2);
        bn_finalize<<<dim3(2), blk, 0, stream>>>(
            stats2, g2 + (size_t)l * DIM, be2 + (size_t)l * DIM, ab2, DIM);

        // next-layer node table: hnb = fp16(relu(bn2(h2))) — last layer pools
        if (l < N_LAYERS - 1)
            bn_apply_h<<<dim3((N_NODES * 80 + 255) / 256), blk, 0, stream>>>(
                h2, ab2, hnb);
    }

    // ---- mean pool with fused last-BN affine + head ----
    pool_seg_bn<<<dim3(N_GRAPHS), blk, 0, stream>>>(h2, gid, ab2, hg);
    sgemm_bias<<<dim3((N_GRAPHS + 63) / 64, (OUTD + 63) / 64), blk, 0, stream>>>(
        hg, pred_W, pred_b, out, N_GRAPHS, OUTD, DIM);
}

// Round 9
// 1766.386 us; speedup vs baseline: 1.1552x; 1.0473x over previous
//
#include <hip/hip_runtime.h>
#include <hip/hip_fp16.h>

#define N_NODES 50000
#define N_EDGES 800000
#define N_GRAPHS 256
#define N_LAYERS 3
#define DIM 300
#define NFEAT 128
#define EFEAT 16
#define OUTD 128
#define BN_EPS 1e-5f
#define HSTRIDE 320   // fp16 node-row stride (300 + zero pad to 320)

typedef __attribute__((ext_vector_type(8))) _Float16 hfrag8; // 8 fp16 = 4 VGPR (MFMA A/B)
typedef __attribute__((ext_vector_type(4))) float facc4;     // MFMA C/D
typedef __attribute__((ext_vector_type(4))) unsigned short us4;
typedef __attribute__((ext_vector_type(8))) unsigned short us8;
typedef __attribute__((ext_vector_type(4))) unsigned int ui4;

// ---------------- bf16 helpers (RNE) ----------------
__device__ __forceinline__ unsigned short f2bf(float f) {
    unsigned u = __float_as_uint(f);
    unsigned r = ((u >> 16) & 1u) + 0x7fffu;
    return (unsigned short)((u + r) >> 16);
}
__device__ __forceinline__ float bf2f(unsigned short h) {
    return __uint_as_float(((unsigned)h) << 16);
}
// fp16 pack/unpack (single v_cvt each)
__device__ __forceinline__ unsigned short f2h(float f) {
    return __half_as_ushort(__float2half(f));
}
__device__ __forceinline__ float h2f(unsigned short u) {
    return __half2float(__ushort_as_half(u));
}

// v_dot2_f32_bf16: 2 bf16 MACs per instruction (gather ef@eW). Guarded.
#if __has_builtin(__builtin_amdgcn_fdot2_f32_bf16)
#define GATHER_DOT2 1
typedef __attribute__((ext_vector_type(2))) __bf16 bf16x2_t;
__device__ __forceinline__ float dot2bf(unsigned a, unsigned b, float c) {
    return __builtin_amdgcn_fdot2_f32_bf16(
        __builtin_bit_cast(bf16x2_t, a), __builtin_bit_cast(bf16x2_t, b), c, false);
}
#else
#define GATHER_DOT2 0
#endif

// async global->LDS, 16B per lane. LDS dest = uniform base + lane*16 (HW rule).
__device__ __forceinline__ void load_lds16(const void* gsrc, void* ldsdst) {
    __builtin_amdgcn_global_load_lds(
        (const __attribute__((address_space(1))) unsigned int*)gsrc,
        (__attribute__((address_space(3))) unsigned int*)ldsdst,
        16, 0, 0);
}

// fp16 MFMA single-pass (round-8 proven: faster AND more accurate than bf16 hi/lo)
#define MFMAH(a, b, c) __builtin_amdgcn_mfma_f32_16x16x32_f16(a, b, c, 0, 0, 0)

// ---------------------------------------------------------------------------
// fp32 -> fp16, vectorized (encoder A operand)
// ---------------------------------------------------------------------------
__global__ __launch_bounds__(256) void toh4(
    const float* __restrict__ x, unsigned short* __restrict__ H, int n4)
{
    int i = blockIdx.x * 256 + threadIdx.x;
    if (i >= n4) return;
    float4 v = ((const float4*)x)[i];
    us4 h;
    h.x = f2h(v.x); h.y = f2h(v.y); h.z = f2h(v.z); h.w = f2h(v.w);
    ((us4*)H)[i] = h;
}

// ---------------------------------------------------------------------------
// weight conversion: W fp32 [K][N] -> transposed padded fp16 plane [Np][Kp]
// ---------------------------------------------------------------------------
__global__ __launch_bounds__(256) void conv_wt(
    const float* __restrict__ W, unsigned short* __restrict__ H,
    int K, int N, int Kp, int Np)
{
    int idx = blockIdx.x * 256 + threadIdx.x;
    if (idx >= Np * Kp) return;
    int n = idx / Kp;
    int k = idx - n * Kp;
    float v = (n < N && k < K) ? W[(size_t)k * N + n] : 0.f;
    H[idx] = f2h(v);
}

// ---------------------------------------------------------------------------
// fp16 MFMA GEMM: A fp16 [M][Kp]; B transposed fp16 plane [Np][Kp].
// OUTPUT fp16 (round-9: all intermediates fp16 — x1/hnb were the dominant
// removable traffic). Writes cols < ldh (stride ldh); cols >= N get 0 bias
// (B rows there are zero-padded -> acc 0 -> writes 0: encoder's hnb pad).
// Optional column-stat epilogue (BN) on fp32 acc.
// ---------------------------------------------------------------------------
__global__ __launch_bounds__(256, 2) void gemm_pp(
    const unsigned short* __restrict__ Ah, const unsigned short* __restrict__ Bt,
    const float* __restrict__ bias, unsigned short* __restrict__ Ch,
    int M, int N, int Kp, int ldh, float* __restrict__ stats)
{
    __shared__ unsigned short lds[8192];   // 16 KB: A(0..4095) | B(4096..8191)
    const int tid = threadIdx.x;
    const int lane = tid & 63;
    const int w = tid >> 6;
    const int m0 = blockIdx.y * 128;
    const int n0 = blockIdx.x * 128;
    const int wm = (w & 1) * 64;
    const int wn = (w >> 1) * 64;

    const int srow = lane >> 2;
    const int scol = (lane & 3) * 8;

    const unsigned short* gp[4];
    unsigned loff[4];
#pragma unroll
    for (int i = 0; i < 4; ++i) {
        int c = w * 4 + i;                 // 0..7 A rows, 8..15 B rows
        const unsigned short* pl = (c < 8) ? Ah : Bt;
        int rowg;
        if (c < 8) {
            rowg = m0 + (c & 7) * 16 + srow;
            rowg = min(rowg, M - 1);
        } else {
            rowg = n0 + (c & 7) * 16 + srow;
        }
        gp[i] = pl + (size_t)rowg * Kp + scol;
        loff[i] = c * 512;
    }

    facc4 acc[4][4];
    facc4 zero = {0.f, 0.f, 0.f, 0.f};
#pragma unroll
    for (int i = 0; i < 4; ++i)
#pragma unroll
        for (int j = 0; j < 4; ++j) acc[i][j] = zero;

    const int fr = lane & 15;
    const int fq = (lane >> 4) * 8;

    for (int k0 = 0; k0 < Kp; k0 += 32) {
#pragma unroll
        for (int i = 0; i < 4; ++i) {
            load_lds16(gp[i], &lds[loff[i]]);
            gp[i] += 32;
        }
        __syncthreads();

        hfrag8 ah[4], bh[4];
#pragma unroll
        for (int t = 0; t < 4; ++t) {
            int ar = wm + t * 16 + fr;
            ah[t] = *(const hfrag8*)&lds[ar * 32 + fq];
            int br = wn + t * 16 + fr;
            bh[t] = *(const hfrag8*)&lds[4096 + br * 32 + fq];
        }
#pragma unroll
        for (int i = 0; i < 4; ++i)
#pragma unroll
            for (int j = 0; j < 4; ++j)
                acc[i][j] = MFMAH(ah[i], bh[j], acc[i][j]);
        __syncthreads();
    }

    // epilogue: C/D layout col=lane&15, row=(lane>>4)*4+reg; fp16 out
#pragma unroll
    for (int i = 0; i < 4; ++i)
#pragma unroll
        for (int j = 0; j < 4; ++j) {
            int col = n0 + wn + j * 16 + (lane & 15);
            if (col >= ldh) continue;
            float bv = (col < N) ? bias[col] : 0.f;
#pragma unroll
            for (int r = 0; r < 4; ++r) {
                int row = m0 + wm + i * 16 + (lane >> 4) * 4 + r;
                if (row < M)
                    Ch[(size_t)row * ldh + col] = f2h(acc[i][j][r] + bv);
            }
        }

    if (stats != nullptr) {
#pragma unroll
        for (int j = 0; j < 4; ++j) {
            int col = n0 + wn + j * 16 + (lane & 15);
            float cs = 0.f, cq = 0.f;
            if (col < N) {
                float bv = bias[col];
#pragma unroll
                for (int i = 0; i < 4; ++i)
#pragma unroll
                    for (int r = 0; r < 4; ++r) {
                        int row = m0 + wm + i * 16 + (lane >> 4) * 4 + r;
                        if (row < M) {
                            float y = acc[i][j][r] + bv;
                            cs += y;
                            cq = fmaf(y, y, cq);
                        }
                    }
            }
            cs += __shfl_xor(cs, 16, 64); cq += __shfl_xor(cq, 16, 64);
            cs += __shfl_xor(cs, 32, 64); cq += __shfl_xor(cq, 32, 64);
            if ((lane >> 4) == 0 && col < N) {
                atomicAdd(&stats[col], cs);
                atomicAdd(&stats[N + col], cq);
            }
        }
    }
}

// ---------------------------------------------------------------------------
// fp16 MFMA GEMM, A fp16 with fused BN-affine+ReLU applied during staging
// (abn = [a K | b K], y = relu(x*a+b)) -> fp16 LDS. Output fp16 (stride N).
// Column-stat epilogue for BN2.
// ---------------------------------------------------------------------------
__global__ __launch_bounds__(256, 2) void gemm_af(
    const unsigned short* __restrict__ A, const unsigned short* __restrict__ Bt,
    const float* __restrict__ bias, unsigned short* __restrict__ Ch,
    int M, int N, int K, int Kp,
    const float* __restrict__ abn, float* __restrict__ stats)
{
    __shared__ unsigned short lds[8192];   // 16 KB: A(0..4095) | B(4096..8191)
    const int tid = threadIdx.x;
    const int lane = tid & 63;
    const int w = tid >> 6;
    const int m0 = blockIdx.y * 128;
    const int n0 = blockIdx.x * 128;
    const int wm = (w & 1) * 64;
    const int wn = (w >> 1) * 64;

    const int srow = lane >> 2;
    const int scol = (lane & 3) * 8;

    const unsigned short* gpb[2];
    unsigned loffb[2];
#pragma unroll
    for (int i = 0; i < 2; ++i) {
        int c = w * 2 + i;                 // 0..7 B rows
        int rowg = n0 + c * 16 + srow;
        gpb[i] = Bt + (size_t)rowg * Kp + scol;
        loffb[i] = 4096 + c * 512;
    }

    facc4 acc[4][4];
    facc4 zero = {0.f, 0.f, 0.f, 0.f};
#pragma unroll
    for (int i = 0; i < 4; ++i)
#pragma unroll
        for (int j = 0; j < 4; ++j) acc[i][j] = zero;

    const int fr = lane & 15;
    const int fq = (lane >> 4) * 8;

    for (int k0 = 0; k0 < Kp; k0 += 32) {
#pragma unroll
        for (int i = 0; i < 2; ++i) {
            load_lds16(gpb[i], &lds[loffb[i]]);
            gpb[i] += 32;
        }
        // A fp16 -> BN affine + relu -> fp16 into LDS (128 rows x 32 k)
#pragma unroll
        for (int i = 0; i < 4; ++i) {
            int idx = tid + i * 256;
            int row = idx >> 3;
            int q4 = idx & 7;
            int rg = min(m0 + row, M - 1);
            int kk = k0 + q4 * 4;
            us4 h;
            if (kk < K) {
                us4 v = *(const us4*)&A[(size_t)rg * K + kk];
                float4 sa = *(const float4*)&abn[kk];
                float4 sb = *(const float4*)&abn[K + kk];
                h.x = f2h(fmaxf(fmaf(h2f(v.x), sa.x, sb.x), 0.f));
                h.y = f2h(fmaxf(fmaf(h2f(v.y), sa.y, sb.y), 0.f));
                h.z = f2h(fmaxf(fmaf(h2f(v.z), sa.z, sb.z), 0.f));
                h.w = f2h(fmaxf(fmaf(h2f(v.w), sa.w, sb.w), 0.f));
            } else {
                h.x = 0; h.y = 0; h.z = 0; h.w = 0;
            }
            *(us4*)&lds[row * 32 + q4 * 4] = h;
        }
        __syncthreads();

        hfrag8 ah[4], bh[4];
#pragma unroll
        for (int t = 0; t < 4; ++t) {
            int ar = wm + t * 16 + fr;
            ah[t] = *(const hfrag8*)&lds[ar * 32 + fq];
            int br = wn + t * 16 + fr;
            bh[t] = *(const hfrag8*)&lds[4096 + br * 32 + fq];
        }
#pragma unroll
        for (int i = 0; i < 4; ++i)
#pragma unroll
            for (int j = 0; j < 4; ++j)
                acc[i][j] = MFMAH(ah[i], bh[j], acc[i][j]);
        __syncthreads();
    }

#pragma unroll
    for (int i = 0; i < 4; ++i)
#pragma unroll
        for (int j = 0; j < 4; ++j) {
            int col = n0 + wn + j * 16 + (lane & 15);
            if (col >= N) continue;
            float bv = bias[col];
#pragma unroll
            for (int r = 0; r < 4; ++r) {
                int row = m0 + wm + i * 16 + (lane >> 4) * 4 + r;
                if (row < M)
                    Ch[(size_t)row * N + col] = f2h(acc[i][j][r] + bv);
            }
        }

    if (stats != nullptr) {
#pragma unroll
        for (int j = 0; j < 4; ++j) {
            int col = n0 + wn + j * 16 + (lane & 15);
            float cs = 0.f, cq = 0.f;
            if (col < N) {
                float bv = bias[col];
#pragma unroll
                for (int i = 0; i < 4; ++i)
#pragma unroll
                    for (int r = 0; r < 4; ++r) {
                        int row = m0 + wm + i * 16 + (lane >> 4) * 4 + r;
                        if (row < M) {
                            float y = acc[i][j][r] + bv;
                            cs += y;
                            cq = fmaf(y, y, cq);
                        }
                    }
            }
            cs += __shfl_xor(cs, 16, 64); cq += __shfl_xor(cq, 16, 64);
            cs += __shfl_xor(cs, 32, 64); cq += __shfl_xor(cq, 32, 64);
            if ((lane >> 4) == 0 && col < N) {
                atomicAdd(&stats[col], cs);
                atomicAdd(&stats[N + col], cq);
            }
        }
    }
}

// ---------------------------------------------------------------------------
// CSR build (dst-sorted). P[v] = end offset after fill.
// ---------------------------------------------------------------------------
__global__ __launch_bounds__(256) void csr_count(const int* __restrict__ dst, int* __restrict__ P)
{
    int e = blockIdx.x * 256 + threadIdx.x;
    if (e < N_EDGES) atomicAdd(&P[dst[e] + 1], 1);
}

__global__ __launch_bounds__(1024) void csr_scan(int* __restrict__ P)
{
    __shared__ int part[1024];
    const int t = threadIdx.x;
    const int CH = 49;
    int i0 = t * CH;
    int s = 0;
    for (int i = i0; i < i0 + CH; ++i) {
        if (i <= N_NODES) { s += P[i]; P[i] = s; }
    }
    part[t] = s;
    __syncthreads();
    if (t == 0) {
        int run = 0;
        for (int k = 0; k < 1024; ++k) { int tmp = part[k]; part[k] = run; run += tmp; }
    }
    __syncthreads();
    int off = part[t];
    for (int i = i0; i < i0 + CH; ++i) {
        if (i <= N_NODES) P[i] += off;
    }
}

__global__ __launch_bounds__(256) void csr_fill(
    const int* __restrict__ dst, int* __restrict__ P, int* __restrict__ eids)
{
    int e = blockIdx.x * 256 + threadIdx.x;
    if (e < N_EDGES) {
        int pos = atomicAdd(&P[dst[e]], 1);
        eids[pos] = e;
    }
}

// ---------------------------------------------------------------------------
// Re-sort src + edge_feat(->bf16) into CSR edge order. Runs once.
// ---------------------------------------------------------------------------
__global__ __launch_bounds__(256) void edge_pack_bf(
    const int* __restrict__ src, const int* __restrict__ eids,
    const float* __restrict__ edge_feat, int* __restrict__ es,
    unsigned short* __restrict__ efsb)
{
    int j = blockIdx.x * 256 + threadIdx.x;
    if (j >= N_EDGES) return;
    int e = eids[j];
    es[j] = src[e];
    const float* sp = edge_feat + (size_t)e * EFEAT;
    us8 o0, o1;
#pragma unroll
    for (int k = 0; k < 8; ++k) {
        o0[k] = f2bf(sp[k]);
        o1[k] = f2bf(sp[8 + k]);
    }
    *(us8*)&efsb[(size_t)j * EFEAT] = o0;
    *(us8*)&efsb[(size_t)j * EFEAT + 8] = o1;
}

// ---------------------------------------------------------------------------
// Gather aggregation v13 (195us/layer proven): wide-load lane->dim mapping
// (q<4: d=4*lane+q via ushort4; q==4: d=256+lane), fp16 row table, dot2
// ef@eW. Output aggH fp16 (feeds the fp16 MFMA GEMM directly).
// ---------------------------------------------------------------------------
__global__ __launch_bounds__(256) void gather_agg7(
    const unsigned short* __restrict__ hnb, const unsigned short* __restrict__ efsb,
    const int* __restrict__ es, const int* __restrict__ P,
    const float* __restrict__ eW, const float* __restrict__ eb,
    unsigned short* __restrict__ aggH)
{
    const int v = blockIdx.x * 4 + (threadIdx.x >> 6);
    if (v >= N_NODES) return;
    const int lane = threadIdx.x & 63;

    // lane-owned dims: q<4 -> d=4*lane+q (0..255); q==4 -> d=256+lane (256..319)
    float acc[5];
    float ebv[5];
    {
        us4 r4 = *(const us4*)&hnb[(size_t)v * HSTRIDE + 4 * lane];
        acc[0] = h2f(r4.x); acc[1] = h2f(r4.y);
        acc[2] = h2f(r4.z); acc[3] = h2f(r4.w);
        acc[4] = h2f(hnb[(size_t)v * HSTRIDE + 256 + lane]);
    }
#if GATHER_DOT2
    unsigned wpk[8][5];   // feature-pair p=(2p,2p+1), owned-dim slot q
#pragma unroll
    for (int q = 0; q < 5; ++q) {
        int d = (q < 4) ? 4 * lane + q : 256 + lane;
        bool dv = d < DIM;
        ebv[q] = dv ? eb[d] : 0.f;
#pragma unroll
        for (int p = 0; p < 8; ++p) {
            unsigned short h0 = dv ? f2bf(eW[(2 * p) * DIM + d]) : (unsigned short)0;
            unsigned short h1 = dv ? f2bf(eW[(2 * p + 1) * DIM + d]) : (unsigned short)0;
            wpk[p][q] = (unsigned)h0 | ((unsigned)h1 << 16);
        }
    }
#else
    float wr[EFEAT][5];
#pragma unroll
    for (int q = 0; q < 5; ++q) {
        int d = (q < 4) ? 4 * lane + q : 256 + lane;
        bool dv = d < DIM;
        ebv[q] = dv ? eb[d] : 0.f;
#pragma unroll
        for (int k = 0; k < EFEAT; ++k)
            wr[k][q] = dv ? eW[k * DIM + d] : 0.f;
    }
#endif

    const int j0 = (v == 0) ? 0 : P[v - 1];
    const int j1 = P[v];

    int j = j0;
    for (; j + 4 <= j1; j += 4) {
        int s0 = __builtin_amdgcn_readfirstlane(es[j]);
        int s1 = __builtin_amdgcn_readfirstlane(es[j + 1]);
        int s2 = __builtin_amdgcn_readfirstlane(es[j + 2]);
        int s3 = __builtin_amdgcn_readfirstlane(es[j + 3]);
        const unsigned short* __restrict__ h0 = hnb + (size_t)s0 * HSTRIDE;
        const unsigned short* __restrict__ h1 = hnb + (size_t)s1 * HSTRIDE;
        const unsigned short* __restrict__ h2p = hnb + (size_t)s2 * HSTRIDE;
        const unsigned short* __restrict__ h3 = hnb + (size_t)s3 * HSTRIDE;
        us4 r4[4];
        unsigned short r1[4];
        r4[0] = *(const us4*)&h0[4 * lane];  r1[0] = h0[256 + lane];
        r4[1] = *(const us4*)&h1[4 * lane];  r1[1] = h1[256 + lane];
        r4[2] = *(const us4*)&h2p[4 * lane]; r1[2] = h2p[256 + lane];
        r4[3] = *(const us4*)&h3[4 * lane];  r1[3] = h3[256 + lane];
#if GATHER_DOT2
        ui4 pa[4][2];
#pragma unroll
        for (int u = 0; u < 4; ++u) {
            pa[u][0] = *(const ui4*)&efsb[(size_t)(j + u) * EFEAT];
            pa[u][1] = *(const ui4*)&efsb[(size_t)(j + u) * EFEAT + 8];
        }
#pragma unroll
        for (int u = 0; u < 4; ++u) {
            float hv[5];
            hv[0] = h2f(r4[u][0]); hv[1] = h2f(r4[u][1]);
            hv[2] = h2f(r4[u][2]); hv[3] = h2f(r4[u][3]);
            hv[4] = h2f(r1[u]);
#pragma unroll
            for (int q = 0; q < 5; ++q) {
                float he = ebv[q];
                he = dot2bf(pa[u][0][0], wpk[0][q], he);
                he = dot2bf(pa[u][0][1], wpk[1][q], he);
                he = dot2bf(pa[u][0][2], wpk[2][q], he);
                he = dot2bf(pa[u][0][3], wpk[3][q], he);
                he = dot2bf(pa[u][1][0], wpk[4][q], he);
                he = dot2bf(pa[u][1][1], wpk[5][q], he);
                he = dot2bf(pa[u][1][2], wpk[6][q], he);
                he = dot2bf(pa[u][1][3], wpk[7][q], he);
                acc[q] += fmaxf(hv[q] + he, 0.f);
            }
        }
#else
        us8 pk[4][2];
#pragma unroll
        for (int u = 0; u < 4; ++u) {
            pk[u][0] = *(const us8*)&efsb[(size_t)(j + u) * EFEAT];
            pk[u][1] = *(const us8*)&efsb[(size_t)(j + u) * EFEAT + 8];
        }
#pragma unroll
        for (int u = 0; u < 4; ++u) {
            float hv[5];
            hv[0] = h2f(r4[u][0]); hv[1] = h2f(r4[u][1]);
            hv[2] = h2f(r4[u][2]); hv[3] = h2f(r4[u][3]);
            hv[4] = h2f(r1[u]);
            float ef[EFEAT];
#pragma unroll
            for (int k = 0; k < 8; ++k) {
                ef[k] = bf2f(pk[u][0][k]);
                ef[8 + k] = bf2f(pk[u][1][k]);
            }
#pragma unroll
            for (int q = 0; q < 5; ++q) {
                float he = ebv[q];
#pragma unroll
                for (int k = 0; k < EFEAT; ++k) he = fmaf(ef[k], wr[k][q], he);
                acc[q] += fmaxf(hv[q] + he, 0.f);
            }
        }
#endif
    }
    for (; j < j1; ++j) {
        int s = __builtin_amdgcn_readfirstlane(es[j]);
        const unsigned short* __restrict__ hp = hnb + (size_t)s * HSTRIDE;
        us4 r4 = *(const us4*)&hp[4 * lane];
        unsigned short r1 = hp[256 + lane];
        float hv[5];
        hv[0] = h2f(r4.x); hv[1] = h2f(r4.y);
        hv[2] = h2f(r4.z); hv[3] = h2f(r4.w);
        hv[4] = h2f(r1);
#if GATHER_DOT2
        ui4 p0 = *(const ui4*)&efsb[(size_t)j * EFEAT];
        ui4 p1 = *(const ui4*)&efsb[(size_t)j * EFEAT + 8];
#pragma unroll
        for (int q = 0; q < 5; ++q) {
            float he = ebv[q];
            he = dot2bf(p0[0], wpk[0][q], he);
            he = dot2bf(p0[1], wpk[1][q], he);
            he = dot2bf(p0[2], wpk[2][q], he);
            he = dot2bf(p0[3], wpk[3][q], he);
            he = dot2bf(p1[0], wpk[4][q], he);
            he = dot2bf(p1[1], wpk[5][q], he);
            he = dot2bf(p1[2], wpk[6][q], he);
            he = dot2bf(p1[3], wpk[7][q], he);
            acc[q] += fmaxf(hv[q] + he, 0.f);
        }
#else
        us8 p0 = *(const us8*)&efsb[(size_t)j * EFEAT];
        us8 p1 = *(const us8*)&efsb[(size_t)j * EFEAT + 8];
        float ef[EFEAT];
#pragma unroll
        for (int k = 0; k < 8; ++k) {
            ef[k] = bf2f(p0[k]);
            ef[8 + k] = bf2f(p1[k]);
        }
#pragma unroll
        for (int q = 0; q < 5; ++q) {
            float he = ebv[q];
#pragma unroll
            for (int k = 0; k < EFEAT; ++k) he = fmaf(ef[k], wr[k][q], he);
            acc[q] += fmaxf(hv[q] + he, 0.f);
        }
#endif
    }

    // write fp16 (GEMM A operand): contiguous us4 + ushort; dims>=300 are 0.
    {
        us4 o;
        o.x = f2h(acc[0]); o.y = f2h(acc[1]);
        o.z = f2h(acc[2]); o.w = f2h(acc[3]);
        *(us4*)&aggH[(size_t)v * 320 + 4 * lane] = o;
        aggH[(size_t)v * 320 + 256 + lane] = f2h(acc[4]);
    }
}

// ---------------------------------------------------------------------------
// BN finalize + apply (apply writes the fp16 node table for the next gather)
// ---------------------------------------------------------------------------
__global__ __launch_bounds__(256) void bn_finalize(
    const float* __restrict__ stats, const float* __restrict__ g,
    const float* __restrict__ beta, float* __restrict__ ab, int C)
{
    int c = blockIdx.x * 256 + threadIdx.x;
    if (c >= C) return;
    const float invN = 1.f / (float)N_NODES;
    float m = stats[c] * invN;
    float v = stats[C + c] * invN - m * m;
    float a = g[c] * rsqrtf(v + BN_EPS);
    ab[c] = a;
    ab[C + c] = beta[c] - m * a;
}

// hnb = relu(h2h*a+b) -> fp16 rows [N][HSTRIDE], zero pad 300..319
// (h2h fp16 [N][300])
__global__ __launch_bounds__(256) void bn_apply_h(
    const unsigned short* __restrict__ x, const float* __restrict__ ab,
    unsigned short* __restrict__ hnb)
{
    int i = blockIdx.x * 256 + threadIdx.x;
    if (i >= N_NODES * 80) return;
    int row = i / 80;
    int q = i - row * 80;
    int c = 4 * q;
    us4 o;
    if (q < 75) {
        us4 v = *(const us4*)&x[(size_t)row * DIM + c];
        const float* a = ab + c;
        const float* bb = ab + DIM + c;
        o.x = f2h(fmaxf(fmaf(h2f(v.x), a[0], bb[0]), 0.f));
        o.y = f2h(fmaxf(fmaf(h2f(v.y), a[1], bb[1]), 0.f));
        o.z = f2h(fmaxf(fmaf(h2f(v.z), a[2], bb[2]), 0.f));
        o.w = f2h(fmaxf(fmaf(h2f(v.w), a[3], bb[3]), 0.f));
    } else {
        o.x = 0; o.y = 0; o.z = 0; o.w = 0;
    }
    *(us4*)&hnb[(size_t)row * HSTRIDE + c] = o;
}

// ---------------------------------------------------------------------------
// Mean pooling fused with last BN affine: hg = a*mean(h2h)+b (h2h fp16).
// ---------------------------------------------------------------------------
__global__ __launch_bounds__(256) void pool_seg_bn(
    const unsigned short* __restrict__ h2, const int* __restrict__ gid,
    const float* __restrict__ ab, float* __restrict__ hg)
{
    const int g = blockIdx.x;
    int lo = 0, hi = N_NODES;
    while (lo < hi) { int mid = (lo + hi) >> 1; if (gid[mid] < g) lo = mid + 1; else hi = mid; }
    int lo2 = lo, hi2 = N_NODES;
    while (lo2 < hi2) { int mid = (lo2 + hi2) >> 1; if (gid[mid] < g + 1) lo2 = mid + 1; else hi2 = mid; }
    const float inv = 1.f / fmaxf((float)(lo2 - lo), 1.f);
    for (int d = threadIdx.x; d < DIM; d += 256) {
        float s = 0.f;
        for (int r = lo; r < lo2; ++r) s += h2f(h2[(size_t)r * DIM + d]);
        hg[(size_t)g * DIM + d] = fmaf(s * inv, ab[d], ab[DIM + d]);
    }
}

// fp32 tiled sgemm for the tiny prediction head
#define TS 64
#define BK 16
#define ASP 68

__global__ __launch_bounds__(256) void sgemm_bias(
    const float* __restrict__ A, const float* __restrict__ B,
    const float* __restrict__ bias, float* __restrict__ C,
    int M, int Ncol, int K)
{
    __shared__ float As[BK][ASP];
    __shared__ float Bs[BK][TS];
    const int tid = threadIdx.x;
    const int bm = blockIdx.x * TS;
    const int bn = blockIdx.y * TS;
    const int tm = (tid >> 4) * 4;
    const int tn = (tid & 15) * 4;
    float acc[4][4] = {};

    for (int k0 = 0; k0 < K; k0 += BK) {
#pragma unroll
        for (int i = 0; i < 4; ++i) {
            int idx = tid + i * 256;
            int m = idx >> 4;
            int k = idx & 15;
            int row = bm + m, kk = k0 + k;
            float v = 0.f;
            if (row < M && kk < K) v = A[(size_t)row * K + kk];
            As[k][m] = v;
        }
#pragma unroll
        for (int i = 0; i < 4; ++i) {
            int idx = tid + i * 256;
            int k = idx >> 6;
            int n = idx & 63;
            int col = bn + n, kk = k0 + k;
            float v = 0.f;
            if (col < Ncol && kk < K) v = B[(size_t)kk * Ncol + col];
            Bs[k][n] = v;
        }
        __syncthreads();
#pragma unroll
        for (int k = 0; k < BK; ++k) {
            float4 av = *(const float4*)&As[k][tm];
            float4 bv = *(const float4*)&Bs[k][tn];
            float a4[4] = {av.x, av.y, av.z, av.w};
            float b4[4] = {bv.x, bv.y, bv.z, bv.w};
#pragma unroll
            for (int i = 0; i < 4; ++i)
#pragma unroll
                for (int j = 0; j < 4; ++j)
                    acc[i][j] = fmaf(a4[i], b4[j], acc[i][j]);
        }
        __syncthreads();
    }

#pragma unroll
    for (int i = 0; i < 4; ++i) {
        int row = bm + tm + i;
        if (row >= M) continue;
#pragma unroll
        for (int j = 0; j < 4; ++j) {
            int col = bn + tn + j;
            if (col < Ncol)
                C[(size_t)row * Ncol + col] = acc[i][j] + bias[col];
        }
    }
}

// ---------------------------------------------------------------------------
extern "C" void kernel_launch(void* const* d_in, const int* in_sizes, int n_in,
                              void* d_out, int out_size, void* d_ws, size_t ws_size,
                              hipStream_t stream)
{
    const float* node_feat = (const float*)d_in[0];
    const float* edge_feat = (const float*)d_in[1];
    const int*   src       = (const int*)d_in[2];
    const int*   dst       = (const int*)d_in[3];
    const int*   gid       = (const int*)d_in[4];
    const float* node_W = (const float*)d_in[6];
    const float* node_b = (const float*)d_in[7];
    const float* edge_W = (const float*)d_in[8];
    const float* edge_b = (const float*)d_in[9];
    const float* W1  = (const float*)d_in[10];
    const float* b1  = (const float*)d_in[11];
    const float* g1  = (const float*)d_in[12];
    const float* be1 = (const float*)d_in[13];
    const float* W2  = (const float*)d_in[14];
    const float* b2  = (const float*)d_in[15];
    const float* g2  = (const float*)d_in[16];
    const float* be2 = (const float*)d_in[17];
    const float* pred_W = (const float*)d_in[18];
    const float* pred_b = (const float*)d_in[19];
    float* out = (float*)d_out;

    // ---- workspace layout (bytes), total < 248.73 MB ----
    // Round-9: ALL intermediates fp16.
    //   h2h  [N][300] fp16 (30MB)  @ base+0
    //   x1h  [N][600] fp16 (60MB)  @ base+60M; hnb [N][320] fp16 (32MB)
    //        aliases its head (lifetime: bn_apply_h(l)/encoder -> gather(l+1),
    //        x1h dead in that window; gemm_pp(l+1) writes x1h only after
    //        gather(l+1) completes).
    //   nfH  [N][128] fp16 (12.8MB) @ base+180M (aggH region — aggH is first
    //        written by gather(0), after the encoder gemm has consumed nfH).
    char* base = (char*)d_ws;
    unsigned short* h2h  = (unsigned short*)(base + 0);        // 30,000,000
    unsigned short* x1h  = (unsigned short*)(base + 60000000); // 60,000,000
    unsigned short* hnb  = x1h;                                // alias (32MB head)
    unsigned short* aggH = (unsigned short*)(base + 180000000);// 32,000,000 (fp16)
    unsigned short* nfH  = aggH;                               // alias (encoder only)
    int*   es            = (int*)(base + 212000000);           // 3,200,000
    unsigned short* efsb = (unsigned short*)(base + 215200000);// 25,600,000
    unsigned short* wtH  = (unsigned short*)(base + 244000000);// <=466,944 (fp16 plane)
    int*   eids          = (int*)(base + 245000000);           // 3,200,000
    int*   P             = (int*)(base + 248200000);           // 200,004
    float* stats         = (float*)(base + 248400016);
    float* ab            = (float*)(base + 248407216);
    float* hg            = (float*)(base + 248414416);         // 307,200
    float* stats2        = stats + 1200;
    float* ab2           = ab + 1200;

    dim3 blk(256);

    // ---- node encoder: hnb = fp16(node_feat @ node_W + node_b), pad to 320 ----
    toh4<<<dim3((N_NODES * NFEAT / 4 + 255) / 256), blk, 0, stream>>>(
        node_feat, nfH, N_NODES * NFEAT / 4);
    conv_wt<<<dim3((384 * 128 + 255) / 256), blk, 0, stream>>>(
        node_W, wtH, NFEAT, DIM, 128, 384);
    gemm_pp<<<dim3(3, 391), blk, 0, stream>>>(
        nfH, wtH, node_b, hnb, N_NODES, DIM, 128, HSTRIDE, nullptr);

    // ---- CSR by dst + packed edge streams (layer-invariant, run once) ----
    hipMemsetAsync(P, 0, (N_NODES + 1) * sizeof(int), stream);
    csr_count<<<dim3((N_EDGES + 255) / 256), blk, 0, stream>>>(dst, P);
    csr_scan<<<dim3(1), dim3(1024), 0, stream>>>(P);
    csr_fill<<<dim3((N_EDGES + 255) / 256), blk, 0, stream>>>(dst, P, eids);
    edge_pack_bf<<<dim3((N_EDGES + 255) / 256), blk, 0, stream>>>(
        src, eids, edge_feat, es, efsb);

    for (int l = 0; l < N_LAYERS; ++l) {
        // aggH = fp16(hnb + sum relu(hnb[src] + he))  [N][320]
        gather_agg7<<<dim3((N_NODES + 3) / 4), blk, 0, stream>>>(
            hnb, efsb, es, P,
            edge_W + (size_t)l * EFEAT * DIM, edge_b + (size_t)l * DIM, aggH);

        hipMemsetAsync(stats, 0, 1800 * sizeof(float), stream);

        // x1h = fp16(agg @ W1 + b1)   [N, 600]  (+ BN1 stats on fp32 acc)
        conv_wt<<<dim3((640 * 320 + 255) / 256), blk, 0, stream>>>(
            W1 + (size_t)l * DIM * 2 * DIM, wtH, DIM, 2 * DIM, 320, 640);
        gemm_pp<<<dim3(5, 391), blk, 0, stream>>>(
            aggH, wtH, b1 + (size_t)l * 2 * DIM, x1h,
            N_NODES, 2 * DIM, 320, 600, stats);
        bn_finalize<<<dim3(3), blk, 0, stream>>>(
            stats, g1 + (size_t)l * 2 * DIM, be1 + (size_t)l * 2 * DIM, ab, 2 * DIM);

        // h2h = fp16(relu(bn1(x1h)) @ W2 + b2)  (BN1 fused in staging; BN2 stats)
        conv_wt<<<dim3((384 * 608 + 255) / 256), blk, 0, stream>>>(
            W2 + (size_t)l * 2 * DIM * DIM, wtH, 2 * DIM, DIM, 608, 384);
        gemm_af<<<dim3(3, 391), blk, 0, stream>>>(
            x1h, wtH, b2 + (size_t)l * DIM, h2h, N_NODES, DIM, 2 * DIM, 608,
            ab, stats2);
        bn_finalize<<<dim3(2), blk, 0, stream>>>(
            stats2, g2 + (size_t)l * DIM, be2 + (size_t)l * DIM, ab2, DIM);

        // next-layer node table: hnb = fp16(relu(bn2(h2h))) — last layer pools
        if (l < N_LAYERS - 1)
            bn_apply_h<<<dim3((N_NODES * 80 + 255) / 256), blk, 0, stream>>>(
                h2h, ab2, hnb);
    }

    // ---- mean pool with fused last-BN affine + head ----
    pool_seg_bn<<<dim3(N_GRAPHS), blk, 0, stream>>>(h2h, gid, ab2, hg);
    sgemm_bias<<<dim3((N_GRAPHS + 63) / 64, (OUTD + 63) / 64), blk, 0, stream>>>(
        hg, pred_W, pred_b, out, N_GRAPHS, OUTD, DIM);
}